// Round 4
// baseline (11659.243 us; speedup 1.0000x reference)
//
#include <hip/hip_runtime.h>
#include <hip/hip_bf16.h>
#include <math.h>

// Problem constants
#define BB 4
#define NH 8
#define NN 8192
#define DD 64
#define MM 256
#define LG 32
#define DIM 512
#define K3 1536
#define KER 33

typedef __hip_bfloat16 bf16;
__device__ __forceinline__ float b2f(bf16 x) { return __bfloat162float(x); }
__device__ __forceinline__ bf16 f2b(float x) { return __float2bfloat16(x); }

// diagnostic fallback: zero the output (absmax would then equal max|ref| ~5.6)
__global__ void zero_out(float* __restrict__ o) {
    o[(size_t)blockIdx.x * 256 + threadIdx.x] = 0.f;
}

// ---------------------------------------------------------------------------
// qkv projection: X[32768,512](f32) @ W[512,1536](f32) -> q,k,v [b,h,n,d] bf16
// ---------------------------------------------------------------------------
__global__ void gemm_qkv(const float* __restrict__ X, const float* __restrict__ W,
                         bf16* __restrict__ q, bf16* __restrict__ k, bf16* __restrict__ v) {
    __shared__ float As[16][64];
    __shared__ float Bs[16][64];
    int tid = threadIdx.x;
    int rowBase = blockIdx.y * 64;
    int colBase = blockIdx.x * 64;
    int ty = tid >> 4, tx = tid & 15;
    float acc[4][4] = {};
    for (int k0 = 0; k0 < DIM; k0 += 16) {
        for (int idx = tid; idx < 64 * 16; idx += 256) {
            int r = idx >> 4, c = idx & 15;
            As[c][r] = X[(size_t)(rowBase + r) * DIM + k0 + c];
        }
        for (int idx = tid; idx < 16 * 64; idx += 256) {
            int r = idx >> 6, c = idx & 63;
            Bs[r][c] = W[(size_t)(k0 + r) * K3 + colBase + c];
        }
        __syncthreads();
#pragma unroll
        for (int kk = 0; kk < 16; kk++) {
            float a[4], b[4];
#pragma unroll
            for (int i = 0; i < 4; i++) a[i] = As[kk][ty * 4 + i];
#pragma unroll
            for (int j = 0; j < 4; j++) b[j] = Bs[kk][tx * 4 + j];
#pragma unroll
            for (int i = 0; i < 4; i++)
#pragma unroll
                for (int j = 0; j < 4; j++) acc[i][j] += a[i] * b[j];
        }
        __syncthreads();
    }
#pragma unroll
    for (int i = 0; i < 4; i++) {
        int r = rowBase + ty * 4 + i;
        int b_ = r >> 13, n_ = r & 8191;
#pragma unroll
        for (int j = 0; j < 4; j++) {
            int c = colBase + tx * 4 + j;
            int part = c / 512, rem = c & 511;
            int h = rem >> 6, d = rem & 63;
            size_t di = ((size_t)(b_ * NH + h) * NN + n_) * DD + d;
            float val = acc[i][j];
            if (part == 0) q[di] = f2b(val * 0.125f);      // scale = d^-0.5
            else if (part == 1) k[di] = f2b(val);
            else v[di] = f2b(val);
        }
    }
}

// out projection: OH[32768,512](bf16) @ Wout[512,512](f32) + bout -> out (f32)
__global__ void gemm_out(const bf16* __restrict__ A, const float* __restrict__ W,
                         const float* __restrict__ bias, float* __restrict__ C) {
    __shared__ float As[16][64];
    __shared__ float Bs[16][64];
    int tid = threadIdx.x;
    int rowBase = blockIdx.y * 64;
    int colBase = blockIdx.x * 64;
    int ty = tid >> 4, tx = tid & 15;
    float acc[4][4] = {};
    for (int k0 = 0; k0 < DIM; k0 += 16) {
        for (int idx = tid; idx < 64 * 16; idx += 256) {
            int r = idx >> 4, c = idx & 15;
            As[c][r] = b2f(A[(size_t)(rowBase + r) * DIM + k0 + c]);
        }
        for (int idx = tid; idx < 16 * 64; idx += 256) {
            int r = idx >> 6, c = idx & 63;
            Bs[r][c] = W[(size_t)(k0 + r) * DIM + colBase + c];
        }
        __syncthreads();
#pragma unroll
        for (int kk = 0; kk < 16; kk++) {
            float a[4], b[4];
#pragma unroll
            for (int i = 0; i < 4; i++) a[i] = As[kk][ty * 4 + i];
#pragma unroll
            for (int j = 0; j < 4; j++) b[j] = Bs[kk][tx * 4 + j];
#pragma unroll
            for (int i = 0; i < 4; i++)
#pragma unroll
                for (int j = 0; j < 4; j++) acc[i][j] += a[i] * b[j];
        }
        __syncthreads();
    }
#pragma unroll
    for (int i = 0; i < 4; i++) {
        int r = rowBase + ty * 4 + i;
#pragma unroll
        for (int j = 0; j < 4; j++) {
            int c = colBase + tx * 4 + j;
            C[(size_t)r * DIM + c] = acc[i][j] + bias[c];
        }
    }
}

// Batched fp32 GEMM: per batch z: C = scale*(A@B) + alpha*I.
__global__ void bgemm(const float* __restrict__ A, const float* __restrict__ B,
                      float* __restrict__ C, int Mm, int Nn, int Kk,
                      float scale, float alpha) {
    __shared__ float As[16][64];
    __shared__ float Bs[16][64];
    int bat = blockIdx.z;
    const float* Ab = A + (size_t)bat * Mm * Kk;
    const float* Bb = B + (size_t)bat * Kk * Nn;
    float* Cb = C + (size_t)bat * Mm * Nn;
    int tid = threadIdx.x;
    int rowBase = blockIdx.y * 64;
    int colBase = blockIdx.x * 64;
    int ty = tid >> 4, tx = tid & 15;
    float acc[4][4] = {};
    for (int k0 = 0; k0 < Kk; k0 += 16) {
        for (int idx = tid; idx < 64 * 16; idx += 256) {
            int r = idx >> 4, c = idx & 15;
            As[c][r] = Ab[(size_t)(rowBase + r) * Kk + k0 + c];
        }
        for (int idx = tid; idx < 16 * 64; idx += 256) {
            int r = idx >> 6, c = idx & 63;
            Bs[r][c] = Bb[(size_t)(k0 + r) * Nn + colBase + c];
        }
        __syncthreads();
#pragma unroll
        for (int kk = 0; kk < 16; kk++) {
            float a[4], b[4];
#pragma unroll
            for (int i = 0; i < 4; i++) a[i] = As[kk][ty * 4 + i];
#pragma unroll
            for (int j = 0; j < 4; j++) b[j] = Bs[kk][tx * 4 + j];
#pragma unroll
            for (int i = 0; i < 4; i++)
#pragma unroll
                for (int j = 0; j < 4; j++) acc[i][j] += a[i] * b[j];
        }
        __syncthreads();
    }
#pragma unroll
    for (int i = 0; i < 4; i++) {
        int r = rowBase + ty * 4 + i;
#pragma unroll
        for (int j = 0; j < 4; j++) {
            int c = colBase + tx * 4 + j;
            float val = scale * acc[i][j];
            if (r == c) val += alpha;
            Cb[(size_t)r * Nn + c] = val;
        }
    }
}

// ---------------------------------------------------------------------------
// landmark means: qL/kL[bh,mi,d] = mean over 32 tokens (bf16 in, fp32 out)
__global__ void landmark_means(const bf16* __restrict__ q, const bf16* __restrict__ k,
                               float* __restrict__ qL, float* __restrict__ kL) {
    int idx = blockIdx.x * 256 + threadIdx.x;   // (bh*256 + mi)*64 + d
    int d = idx & 63;
    int mi = (idx >> 6) & 255;
    int bh = idx >> 14;
    const bf16* qp = q + ((size_t)bh * NN + mi * LG) * DD + d;
    const bf16* kp = k + ((size_t)bh * NN + mi * LG) * DD + d;
    float sq = 0.f, sk = 0.f;
#pragma unroll
    for (int j = 0; j < LG; j++) { sq += b2f(qp[(size_t)j * DD]); sk += b2f(kp[(size_t)j * DD]); }
    qL[idx] = sq * (1.f / LG);
    kL[idx] = sk * (1.f / LG);
}

// attn2 = softmax(qL @ kL^T), one block per row (all fp32)
__global__ void attn2_softmax(const float* __restrict__ qL, const float* __restrict__ kL,
                              float* __restrict__ x2) {
    __shared__ float qs[64];
    __shared__ float red[256];
    int bh = blockIdx.x >> 8, i = blockIdx.x & 255;
    int t = threadIdx.x;
    if (t < 64) qs[t] = qL[((size_t)bh * MM + i) * DD + t];
    __syncthreads();
    const float* kp = kL + ((size_t)bh * MM + t) * DD;
    float l = 0.f;
#pragma unroll
    for (int d = 0; d < 64; d++) l += qs[d] * kp[d];
    red[t] = l; __syncthreads();
    for (int s = 128; s > 0; s >>= 1) { if (t < s) red[t] = fmaxf(red[t], red[t + s]); __syncthreads(); }
    float mx = red[0]; __syncthreads();
    float e = expf(l - mx);
    red[t] = e; __syncthreads();
    for (int s = 128; s > 0; s >>= 1) { if (t < s) red[t] += red[t + s]; __syncthreads(); }
    x2[((size_t)bh * MM + i) * MM + t] = e / red[0];
}

__global__ void init_scal(float* scal) {
    if (threadIdx.x == 0) { scal[0] = 0.f; scal[1] = 0.f; }
}

// max over (bh,i) of sum_j |x|  -> scal[0]
__global__ void rsum_max(const float* __restrict__ x2, float* scal) {
    __shared__ float red[256];
    int t = threadIdx.x;
    float v = fabsf(x2[(size_t)blockIdx.x * MM + t]);
    red[t] = v; __syncthreads();
    for (int s = 128; s > 0; s >>= 1) { if (t < s) red[t] += red[t + s]; __syncthreads(); }
    if (t == 0) atomicMax((unsigned int*)&scal[0], __float_as_uint(red[0]));
}

// max over (bh,j) of sum_i |x|  -> scal[1]
__global__ void csum_max(const float* __restrict__ x2, float* scal) {
    __shared__ float red[256];
    int t = threadIdx.x;
    const float* xp = x2 + (size_t)blockIdx.x * MM * MM;
    float s = 0.f;
    for (int i = 0; i < MM; i++) s += fabsf(xp[(size_t)i * MM + t]);
    red[t] = s; __syncthreads();
    for (int st = 128; st > 0; st >>= 1) { if (t < st) red[t] = fmaxf(red[t], red[t + st]); __syncthreads(); }
    if (t == 0) atomicMax((unsigned int*)&scal[1], __float_as_uint(red[0]));
}

// z = x^T / (scal0*scal1 + 1e-12)
__global__ void z_init(const float* __restrict__ x2, const float* __restrict__ scal,
                       float* __restrict__ z) {
    size_t idx = (size_t)blockIdx.x * 256 + threadIdx.x;
    int j = idx & 255;
    int i = (idx >> 8) & 255;
    size_t bh = idx >> 16;
    float inv = 1.0f / (scal[0] * scal[1] + 1e-12f);
    z[idx] = x2[(bh << 16) + ((size_t)j << 8) + i] * inv;
}

// Bo = 7I - A   (elementwise over batched 256x256)
__global__ void eye7_sub(const float* __restrict__ A, float* __restrict__ Bo) {
    size_t idx = (size_t)blockIdx.x * 256 + threadIdx.x;
    int j = idx & 255;
    int i = (idx >> 8) & 255;
    Bo[idx] = ((i == j) ? 7.0f : 0.0f) - A[idx];
}

// t1 = softmax(qL @ k^T, axis=n) @ v   -- one block per (bh, landmark row)
__global__ void attn3v_kernel(const float* __restrict__ qL, const bf16* __restrict__ k,
                              const bf16* __restrict__ v, float* __restrict__ t1) {
    __shared__ float p[NN];       // 32 KB logits/probs
    __shared__ float red[256];
    __shared__ float qs[64];
    int bh = blockIdx.x >> 8, i = blockIdx.x & 255;
    int t = threadIdx.x;
    if (t < 64) qs[t] = qL[((size_t)bh * MM + i) * DD + t];
    __syncthreads();
    const bf16* kb = k + (size_t)bh * NN * DD;
    float lmax = -1e30f;
    for (int j = t; j < NN; j += 256) {
        const bf16* kp = kb + (size_t)j * DD;
        float l = 0.f;
#pragma unroll
        for (int d = 0; d < 64; d++) l += qs[d] * b2f(kp[d]);
        p[j] = l;
        lmax = fmaxf(lmax, l);
    }
    red[t] = lmax; __syncthreads();
    for (int s = 128; s > 0; s >>= 1) { if (t < s) red[t] = fmaxf(red[t], red[t + s]); __syncthreads(); }
    float mx = red[0]; __syncthreads();
    float lsum = 0.f;
    for (int j = t; j < NN; j += 256) { float e = expf(p[j] - mx); p[j] = e; lsum += e; }
    red[t] = lsum; __syncthreads();
    for (int s = 128; s > 0; s >>= 1) { if (t < s) red[t] += red[t + s]; __syncthreads(); }
    float inv = 1.0f / red[0];
    __syncthreads();
    int d = t & 63, qq = t >> 6;
    const bf16* vb = v + (size_t)bh * NN * DD + d;
    float acc = 0.f;
    for (int j = qq * 2048; j < qq * 2048 + 2048; j++) acc += p[j] * b2f(vb[(size_t)j * DD]);
    red[t] = acc; __syncthreads();
    if (t < 64) {
        float s = red[t] + red[t + 64] + red[t + 128] + red[t + 192];
        t1[((size_t)bh * MM + i) * DD + t] = s * inv;
    }
}

// oh[b,i,h*64+d] = softmax(q_i @ kL^T) @ t2   -- one block per (bh, token)
__global__ void attn1_out(const bf16* __restrict__ q, const float* __restrict__ kL,
                          const float* __restrict__ t2, bf16* __restrict__ oh) {
    __shared__ float qs[64];
    __shared__ float p[256];
    __shared__ float red[256];
    int gr = blockIdx.x;            // bh*N + i
    int bh = gr >> 13, i = gr & 8191;
    int t = threadIdx.x;
    if (t < 64) qs[t] = b2f(q[((size_t)bh * NN + i) * DD + t]);
    __syncthreads();
    const float* kp = kL + ((size_t)bh * MM + t) * DD;
    float l = 0.f;
#pragma unroll
    for (int d = 0; d < 64; d++) l += qs[d] * kp[d];
    red[t] = l; __syncthreads();
    for (int s = 128; s > 0; s >>= 1) { if (t < s) red[t] = fmaxf(red[t], red[t + s]); __syncthreads(); }
    float mx = red[0]; __syncthreads();
    float e = expf(l - mx);
    red[t] = e; __syncthreads();
    for (int s = 128; s > 0; s >>= 1) { if (t < s) red[t] += red[t + s]; __syncthreads(); }
    float inv = 1.0f / red[0];
    __syncthreads();
    p[t] = e * inv; __syncthreads();
    int d = t & 63, qq = t >> 6;
    const float* t2b = t2 + (size_t)bh * MM * DD + d;
    float acc = 0.f;
    for (int j = qq * 64; j < qq * 64 + 64; j++) acc += p[j] * t2b[(size_t)j * DD];
    red[t] = acc; __syncthreads();
    if (t < 64) {
        float s = red[t] + red[t + 64] + red[t + 128] + red[t + 192];
        int b_ = bh >> 3, h = bh & 7;
        oh[((size_t)(b_ * NN + i)) * DIM + h * 64 + t] = f2b(s);
    }
}

// depthwise conv residual: oh += conv(v) along n per head (w is fp32)
__global__ void conv_add(const bf16* __restrict__ v, const float* __restrict__ w,
                         bf16* __restrict__ oh) {
    int idx = blockIdx.x * 256 + threadIdx.x;   // ((b*N+i)*8 + h)*64 + d
    int d = idx & 63;
    int h = (idx >> 6) & 7;
    int rest = idx >> 9;
    int i = rest & 8191;
    int b_ = rest >> 13;
    const bf16* vb = v + ((size_t)(b_ * NH + h) * NN) * DD + d;
    float acc = 0.f;
#pragma unroll
    for (int tt = 0; tt < KER; tt++) {
        int src = i + tt - 16;
        if (src >= 0 && src < NN) acc += w[h * KER + tt] * b2f(vb[(size_t)src * DD]);
    }
    oh[idx] = f2b(b2f(oh[idx]) + acc);
}

// ---------------------------------------------------------------------------

extern "C" void kernel_launch(void* const* d_in, const int* in_sizes, int n_in,
                              void* d_out, int out_size, void* d_ws, size_t ws_size,
                              hipStream_t stream) {
    const float* x    = (const float*)d_in[0];
    const float* Wqkv = (const float*)d_in[1];
    const float* Wout = (const float*)d_in[2];
    const float* bout = (const float*)d_in[3];
    const float* cw   = (const float*)d_in[4];
    float* out = (float*)d_out;

    const size_t SZ_QKV = (size_t)BB * NH * NN * DD;   // 16,777,216 elems
    const size_t SZ_L   = (size_t)BB * NH * MM * DD;   // 524,288
    const size_t SZ_M2  = (size_t)BB * NH * MM * MM;   // 2,097,152

    // --- workspace plumbing (117,440,520 B -- proven to fit in round 3) ---
    // k (bf16, 32 MB) lives in d_out (64 MB fp32, fully overwritten by gemm_out).
    // oh (bf16, 32 MB) aliases the pinv fp32 region (dead after t2 = z@t1).
    char* p = (char*)d_ws;
    bf16* q    = (bf16*)p;  p += SZ_QKV * 2;    // 32 MB
    bf16* v    = (bf16*)p;  p += SZ_QKV * 2;    // 32 MB
    float* x2   = (float*)p; p += SZ_M2 * 4;    // 8 MB each, 40 MB total
    float* z    = (float*)p; p += SZ_M2 * 4;
    float* z2   = (float*)p; p += SZ_M2 * 4;
    float* bufA = (float*)p; p += SZ_M2 * 4;
    float* bufB = (float*)p; p += SZ_M2 * 4;
    float* qL   = (float*)p; p += SZ_L * 4;     // 2 MB each
    float* kL   = (float*)p; p += SZ_L * 4;
    float* t1   = (float*)p; p += SZ_L * 4;
    float* t2   = (float*)p; p += SZ_L * 4;
    float* scal = (float*)p; p += 2 * 4;
    size_t need = (size_t)(p - (char*)d_ws);
    bf16* k  = (bf16*)d_out;   // first 32 MB of the 64 MB fp32 out buffer
    bf16* oh = (bf16*)x2;      // 32 MB over dead pinv region

    if (ws_size < need) {
        zero_out<<<out_size / 256, 256, 0, stream>>>(out);
        return;
    }

    // 1. qkv projection + head transpose + q scaling (fp32 in, bf16 out)
    gemm_qkv<<<dim3(K3 / 64, (BB * NN) / 64), 256, 0, stream>>>(x, Wqkv, q, k, v);
    // 2. landmark means
    landmark_means<<<(BB * NH * MM * DD) / 256, 256, 0, stream>>>(q, k, qL, kL);
    // 3. attn2 = softmax(qL kL^T)
    attn2_softmax<<<BB * NH * MM, 256, 0, stream>>>(qL, kL, x2);
    // 4. pinv init scalars
    init_scal<<<1, 64, 0, stream>>>(scal);
    rsum_max<<<BB * NH * MM, 256, 0, stream>>>(x2, scal);
    csum_max<<<BB * NH, 256, 0, stream>>>(x2, scal);
    z_init<<<(int)(SZ_M2 / 256), 256, 0, stream>>>(x2, scal, z);
    // 5. Newton-Schulz pinv iterations (6 iters, even # of swaps)
    for (int it = 0; it < 6; it++) {
        bgemm<<<dim3(4, 4, BB * NH), 256, 0, stream>>>(x2, z, bufA, MM, MM, MM, 1.f, 0.f);     // A = x z
        eye7_sub<<<(int)(SZ_M2 / 256), 256, 0, stream>>>(bufA, bufB);                           // B1 = 7I - A
        bgemm<<<dim3(4, 4, BB * NH), 256, 0, stream>>>(bufA, bufB, z2, MM, MM, MM, -1.f, 15.f); // Y1 = 15I - A B1
        bgemm<<<dim3(4, 4, BB * NH), 256, 0, stream>>>(bufA, z2, bufB, MM, MM, MM, -1.f, 13.f); // Y2 = 13I - A Y1
        bgemm<<<dim3(4, 4, BB * NH), 256, 0, stream>>>(z, bufB, z2, MM, MM, MM, 0.25f, 0.f);    // z' = 0.25 z Y2
        float* tmp = z; z = z2; z2 = tmp;
    }
    // 6. t1 = softmax(qL k^T) @ v   (k dead after this)
    attn3v_kernel<<<BB * NH * MM, 256, 0, stream>>>(qL, k, v, t1);
    // 7. t2 = z @ t1   (all pinv buffers dead after this)
    bgemm<<<dim3(1, 4, BB * NH), 256, 0, stream>>>(z, t1, t2, MM, DD, MM, 1.f, 0.f);
    // 8. oh = softmax(q kL^T) @ t2   (oh over dead pinv region)
    attn1_out<<<BB * NH * NN, 256, 0, stream>>>(q, kL, t2, oh);
    // 9. oh += depthwise conv residual
    conv_add<<<(BB * NN * DIM) / 256, 256, 0, stream>>>(v, cw, oh);
    // 10. out = oh @ Wout + bout   (fully overwrites d_out; k dead)
    gemm_out<<<dim3(DIM / 64, (BB * NN) / 64), 256, 0, stream>>>(oh, Wout, bout, out);

    (void)in_sizes; (void)n_in; (void)ws_size;
}

// Round 5
// 7150.134 us; speedup vs baseline: 1.6306x; 1.6306x over previous
//
#include <hip/hip_runtime.h>
#include <hip/hip_bf16.h>
#include <math.h>

// Problem constants
#define BB 4
#define NH 8
#define NN 8192
#define DD 64
#define MM 256
#define LG 32
#define DIM 512
#define K3 1536
#define KER 33

typedef __hip_bfloat16 bf16;
__device__ __forceinline__ float b2f(bf16 x) { return __bfloat162float(x); }
__device__ __forceinline__ bf16 f2b(float x) { return __float2bfloat16(x); }
// bf16-pair unpack from a uint32 (element 2m in low half, 2m+1 in high half)
__device__ __forceinline__ float blo(unsigned int u) { return __uint_as_float(u << 16); }
__device__ __forceinline__ float bhi(unsigned int u) { return __uint_as_float(u & 0xffff0000u); }

// diagnostic fallback: zero the output
__global__ void zero_out(float* __restrict__ o) {
    o[(size_t)blockIdx.x * 256 + threadIdx.x] = 0.f;
}

// ---------------------------------------------------------------------------
// qkv projection: X[32768,512](f32) @ W[512,1536](f32) -> q,k,v [b,h,n,d] bf16
// ---------------------------------------------------------------------------
__global__ void gemm_qkv(const float* __restrict__ X, const float* __restrict__ W,
                         bf16* __restrict__ q, bf16* __restrict__ k, bf16* __restrict__ v) {
    __shared__ float As[16][64];
    __shared__ float Bs[16][64];
    int tid = threadIdx.x;
    int rowBase = blockIdx.y * 64;
    int colBase = blockIdx.x * 64;
    int ty = tid >> 4, tx = tid & 15;
    float acc[4][4] = {};
    for (int k0 = 0; k0 < DIM; k0 += 16) {
        for (int idx = tid; idx < 64 * 16; idx += 256) {
            int r = idx >> 4, c = idx & 15;
            As[c][r] = X[(size_t)(rowBase + r) * DIM + k0 + c];
        }
        for (int idx = tid; idx < 16 * 64; idx += 256) {
            int r = idx >> 6, c = idx & 63;
            Bs[r][c] = W[(size_t)(k0 + r) * K3 + colBase + c];
        }
        __syncthreads();
#pragma unroll
        for (int kk = 0; kk < 16; kk++) {
            float a[4], b[4];
#pragma unroll
            for (int i = 0; i < 4; i++) a[i] = As[kk][ty * 4 + i];
#pragma unroll
            for (int j = 0; j < 4; j++) b[j] = Bs[kk][tx * 4 + j];
#pragma unroll
            for (int i = 0; i < 4; i++)
#pragma unroll
                for (int j = 0; j < 4; j++) acc[i][j] += a[i] * b[j];
        }
        __syncthreads();
    }
#pragma unroll
    for (int i = 0; i < 4; i++) {
        int r = rowBase + ty * 4 + i;
        int b_ = r >> 13, n_ = r & 8191;
#pragma unroll
        for (int j = 0; j < 4; j++) {
            int c = colBase + tx * 4 + j;
            int part = c / 512, rem = c & 511;
            int h = rem >> 6, d = rem & 63;
            size_t di = ((size_t)(b_ * NH + h) * NN + n_) * DD + d;
            float val = acc[i][j];
            if (part == 0) q[di] = f2b(val * 0.125f);      // scale = d^-0.5
            else if (part == 1) k[di] = f2b(val);
            else v[di] = f2b(val);
        }
    }
}

// out projection: OH[32768,512](bf16) @ Wout[512,512](f32) + bout -> out (f32)
__global__ void gemm_out(const bf16* __restrict__ A, const float* __restrict__ W,
                         const float* __restrict__ bias, float* __restrict__ C) {
    __shared__ float As[16][64];
    __shared__ float Bs[16][64];
    int tid = threadIdx.x;
    int rowBase = blockIdx.y * 64;
    int colBase = blockIdx.x * 64;
    int ty = tid >> 4, tx = tid & 15;
    float acc[4][4] = {};
    for (int k0 = 0; k0 < DIM; k0 += 16) {
        for (int idx = tid; idx < 64 * 16; idx += 256) {
            int r = idx >> 4, c = idx & 15;
            As[c][r] = b2f(A[(size_t)(rowBase + r) * DIM + k0 + c]);
        }
        for (int idx = tid; idx < 16 * 64; idx += 256) {
            int r = idx >> 6, c = idx & 63;
            Bs[r][c] = W[(size_t)(k0 + r) * DIM + colBase + c];
        }
        __syncthreads();
#pragma unroll
        for (int kk = 0; kk < 16; kk++) {
            float a[4], b[4];
#pragma unroll
            for (int i = 0; i < 4; i++) a[i] = As[kk][ty * 4 + i];
#pragma unroll
            for (int j = 0; j < 4; j++) b[j] = Bs[kk][tx * 4 + j];
#pragma unroll
            for (int i = 0; i < 4; i++)
#pragma unroll
                for (int j = 0; j < 4; j++) acc[i][j] += a[i] * b[j];
        }
        __syncthreads();
    }
#pragma unroll
    for (int i = 0; i < 4; i++) {
        int r = rowBase + ty * 4 + i;
#pragma unroll
        for (int j = 0; j < 4; j++) {
            int c = colBase + tx * 4 + j;
            C[(size_t)r * DIM + c] = acc[i][j] + bias[c];
        }
    }
}

// Batched fp32 GEMM: per batch z: C = scale*(A@B) + alpha*I.
__global__ void bgemm(const float* __restrict__ A, const float* __restrict__ B,
                      float* __restrict__ C, int Mm, int Nn, int Kk,
                      float scale, float alpha) {
    __shared__ float As[16][64];
    __shared__ float Bs[16][64];
    int bat = blockIdx.z;
    const float* Ab = A + (size_t)bat * Mm * Kk;
    const float* Bb = B + (size_t)bat * Kk * Nn;
    float* Cb = C + (size_t)bat * Mm * Nn;
    int tid = threadIdx.x;
    int rowBase = blockIdx.y * 64;
    int colBase = blockIdx.x * 64;
    int ty = tid >> 4, tx = tid & 15;
    float acc[4][4] = {};
    for (int k0 = 0; k0 < Kk; k0 += 16) {
        for (int idx = tid; idx < 64 * 16; idx += 256) {
            int r = idx >> 4, c = idx & 15;
            As[c][r] = Ab[(size_t)(rowBase + r) * Kk + k0 + c];
        }
        for (int idx = tid; idx < 16 * 64; idx += 256) {
            int r = idx >> 6, c = idx & 63;
            Bs[r][c] = Bb[(size_t)(k0 + r) * Nn + colBase + c];
        }
        __syncthreads();
#pragma unroll
        for (int kk = 0; kk < 16; kk++) {
            float a[4], b[4];
#pragma unroll
            for (int i = 0; i < 4; i++) a[i] = As[kk][ty * 4 + i];
#pragma unroll
            for (int j = 0; j < 4; j++) b[j] = Bs[kk][tx * 4 + j];
#pragma unroll
            for (int i = 0; i < 4; i++)
#pragma unroll
                for (int j = 0; j < 4; j++) acc[i][j] += a[i] * b[j];
        }
        __syncthreads();
    }
#pragma unroll
    for (int i = 0; i < 4; i++) {
        int r = rowBase + ty * 4 + i;
#pragma unroll
        for (int j = 0; j < 4; j++) {
            int c = colBase + tx * 4 + j;
            float val = scale * acc[i][j];
            if (r == c) val += alpha;
            Cb[(size_t)r * Nn + c] = val;
        }
    }
}

// ---------------------------------------------------------------------------
// landmark means: qL/kL[bh,mi,d] = mean over 32 tokens (bf16 in, fp32 out)
__global__ void landmark_means(const bf16* __restrict__ q, const bf16* __restrict__ k,
                               float* __restrict__ qL, float* __restrict__ kL) {
    int idx = blockIdx.x * 256 + threadIdx.x;   // (bh*256 + mi)*64 + d
    int d = idx & 63;
    int mi = (idx >> 6) & 255;
    int bh = idx >> 14;
    const bf16* qp = q + ((size_t)bh * NN + mi * LG) * DD + d;
    const bf16* kp = k + ((size_t)bh * NN + mi * LG) * DD + d;
    float sq = 0.f, sk = 0.f;
#pragma unroll
    for (int j = 0; j < LG; j++) { sq += b2f(qp[(size_t)j * DD]); sk += b2f(kp[(size_t)j * DD]); }
    qL[idx] = sq * (1.f / LG);
    kL[idx] = sk * (1.f / LG);
}

// attn2 = softmax(qL @ kL^T), one block per row (all fp32)
__global__ void attn2_softmax(const float* __restrict__ qL, const float* __restrict__ kL,
                              float* __restrict__ x2) {
    __shared__ float qs[64];
    __shared__ float red[256];
    int bh = blockIdx.x >> 8, i = blockIdx.x & 255;
    int t = threadIdx.x;
    if (t < 64) qs[t] = qL[((size_t)bh * MM + i) * DD + t];
    __syncthreads();
    const float4* kp = (const float4*)(kL + ((size_t)bh * MM + t) * DD);
    float l = 0.f;
#pragma unroll
    for (int u = 0; u < 16; u++) {
        float4 kv = kp[u];
        l += qs[u*4+0]*kv.x + qs[u*4+1]*kv.y + qs[u*4+2]*kv.z + qs[u*4+3]*kv.w;
    }
    red[t] = l; __syncthreads();
    for (int s = 128; s > 0; s >>= 1) { if (t < s) red[t] = fmaxf(red[t], red[t + s]); __syncthreads(); }
    float mx = red[0]; __syncthreads();
    float e = __expf(l - mx);
    red[t] = e; __syncthreads();
    for (int s = 128; s > 0; s >>= 1) { if (t < s) red[t] += red[t + s]; __syncthreads(); }
    x2[((size_t)bh * MM + i) * MM + t] = e / red[0];
}

__global__ void init_scal(float* scal) {
    if (threadIdx.x == 0) { scal[0] = 0.f; scal[1] = 0.f; }
}

// max over (bh,i) of sum_j |x|  -> scal[0]
__global__ void rsum_max(const float* __restrict__ x2, float* scal) {
    __shared__ float red[256];
    int t = threadIdx.x;
    float v = fabsf(x2[(size_t)blockIdx.x * MM + t]);
    red[t] = v; __syncthreads();
    for (int s = 128; s > 0; s >>= 1) { if (t < s) red[t] += red[t + s]; __syncthreads(); }
    if (t == 0) atomicMax((unsigned int*)&scal[0], __float_as_uint(red[0]));
}

// max over (bh,j) of sum_i |x|  -> scal[1]
__global__ void csum_max(const float* __restrict__ x2, float* scal) {
    __shared__ float red[256];
    int t = threadIdx.x;
    const float* xp = x2 + (size_t)blockIdx.x * MM * MM;
    float s = 0.f;
    for (int i = 0; i < MM; i++) s += fabsf(xp[(size_t)i * MM + t]);
    red[t] = s; __syncthreads();
    for (int st = 128; st > 0; st >>= 1) { if (t < st) red[t] = fmaxf(red[t], red[t + st]); __syncthreads(); }
    if (t == 0) atomicMax((unsigned int*)&scal[1], __float_as_uint(red[0]));
}

// z = x^T / (scal0*scal1 + 1e-12)
__global__ void z_init(const float* __restrict__ x2, const float* __restrict__ scal,
                       float* __restrict__ z) {
    size_t idx = (size_t)blockIdx.x * 256 + threadIdx.x;
    int j = idx & 255;
    int i = (idx >> 8) & 255;
    size_t bh = idx >> 16;
    float inv = 1.0f / (scal[0] * scal[1] + 1e-12f);
    z[idx] = x2[(bh << 16) + ((size_t)j << 8) + i] * inv;
}

// Bo = 7I - A   (elementwise over batched 256x256)
__global__ void eye7_sub(const float* __restrict__ A, float* __restrict__ Bo) {
    size_t idx = (size_t)blockIdx.x * 256 + threadIdx.x;
    int j = idx & 255;
    int i = (idx >> 8) & 255;
    Bo[idx] = ((i == j) ? 7.0f : 0.0f) - A[idx];
}

// ---------------------------------------------------------------------------
// t1 = softmax(qL @ k^T, axis=n) @ v  -- one block per (bh, landmark row)
// Vectorized: QK^T via uint4 (8 bf16) loads, 8 lanes/row, shfl reduce;
// PV via uint (bf162) loads, 2 d/lane, 8 j-groups.
__global__ void attn3v_kernel(const float* __restrict__ qL, const bf16* __restrict__ k,
                              const bf16* __restrict__ v, float* __restrict__ t1) {
    __shared__ float p[NN];       // 32 KB logits/probs (also scratch for final reduce)
    __shared__ float red[256];
    __shared__ float qs[64];
    int bh = blockIdx.x >> 8, i = blockIdx.x & 255;
    int t = threadIdx.x;
    if (t < 64) qs[t] = qL[((size_t)bh * MM + i) * DD + t];
    __syncthreads();
    // ---- phase 1: logits. 8 lanes cover one 128B k-row; wave = 8 rows = 1KB coalesced.
    int sub = t & 7;           // which 16B slice of the row
    int jofs = t >> 3;         // 0..31 (row offset within a 32-row batch)
    float qr[8];
#pragma unroll
    for (int u = 0; u < 8; u++) qr[u] = qs[sub * 8 + u];
    const uint4* kb = (const uint4*)(k + (size_t)bh * NN * DD);
    float lmax = -1e30f;
#pragma unroll 4
    for (int j0 = 0; j0 < NN; j0 += 32) {
        int j = j0 + jofs;
        uint4 pk = kb[(size_t)j * 8 + sub];
        float l;
        l  = qr[0] * blo(pk.x) + qr[1] * bhi(pk.x);
        l += qr[2] * blo(pk.y) + qr[3] * bhi(pk.y);
        l += qr[4] * blo(pk.z) + qr[5] * bhi(pk.z);
        l += qr[6] * blo(pk.w) + qr[7] * bhi(pk.w);
        l += __shfl_xor(l, 1);
        l += __shfl_xor(l, 2);
        l += __shfl_xor(l, 4);
        if (sub == 0) p[j] = l;
        lmax = fmaxf(lmax, l);
    }
    red[t] = lmax; __syncthreads();
    for (int s = 128; s > 0; s >>= 1) { if (t < s) red[t] = fmaxf(red[t], red[t + s]); __syncthreads(); }
    float mx = red[0]; __syncthreads();
    float lsum = 0.f;
    for (int j = t; j < NN; j += 256) { float e = __expf(p[j] - mx); p[j] = e; lsum += e; }
    red[t] = lsum; __syncthreads();
    for (int s = 128; s > 0; s >>= 1) { if (t < s) red[t] += red[t + s]; __syncthreads(); }
    float inv = 1.0f / red[0];
    __syncthreads();
    // ---- phase 2: PV. lane handles d-pair (2*dp, 2*dp+1), 8 groups of 1024 j.
    int dp = t & 31;
    int qq = t >> 5;           // 0..7
    const unsigned int* vb = (const unsigned int*)(v + (size_t)bh * NN * DD) + dp;
    float a0 = 0.f, a1 = 0.f;
#pragma unroll 4
    for (int j = qq * 1024; j < qq * 1024 + 1024; j++) {
        unsigned int pv = vb[(size_t)j * 32];
        float pj = p[j];
        a0 += pj * blo(pv);
        a1 += pj * bhi(pv);
    }
    __syncthreads();   // all p reads done before overwriting p as scratch
    p[qq * 64 + 2 * dp]     = a0;
    p[qq * 64 + 2 * dp + 1] = a1;
    __syncthreads();
    if (t < 64) {
        float s = 0.f;
#pragma unroll
        for (int g = 0; g < 8; g++) s += p[g * 64 + t];
        t1[((size_t)bh * MM + i) * DD + t] = s * inv;
    }
}

// oh[b,i,h*64+d] = softmax(q_i @ kL^T) @ t2  -- one block per (bh, token)
// Vectorized: float4 kL dot, float2 PV with 8 j-groups.
__global__ void attn1_out(const bf16* __restrict__ q, const float* __restrict__ kL,
                          const float* __restrict__ t2, bf16* __restrict__ oh) {
    __shared__ float qs[64];
    __shared__ float p[256];
    __shared__ float red[256];
    __shared__ float sc[512];
    int gr = blockIdx.x;            // bh*N + i
    int bh = gr >> 13, i = gr & 8191;
    int t = threadIdx.x;
    if (t < 64) qs[t] = b2f(q[((size_t)bh * NN + i) * DD + t]);
    __syncthreads();
    const float4* kp = (const float4*)(kL + ((size_t)bh * MM + t) * DD);
    float l = 0.f;
#pragma unroll
    for (int u = 0; u < 16; u++) {
        float4 kv = kp[u];
        l += qs[u*4+0]*kv.x + qs[u*4+1]*kv.y + qs[u*4+2]*kv.z + qs[u*4+3]*kv.w;
    }
    red[t] = l; __syncthreads();
    for (int s = 128; s > 0; s >>= 1) { if (t < s) red[t] = fmaxf(red[t], red[t + s]); __syncthreads(); }
    float mx = red[0]; __syncthreads();
    float e = __expf(l - mx);
    red[t] = e; __syncthreads();
    for (int s = 128; s > 0; s >>= 1) { if (t < s) red[t] += red[t + s]; __syncthreads(); }
    float inv = 1.0f / red[0];
    __syncthreads();
    p[t] = e * inv; __syncthreads();
    // PV: lane = d-pair (2*dp, 2*dp+1), 8 groups of 32 rows of t2 (fp32)
    int dp = t & 31;
    int qq = t >> 5;
    const float2* t2b = (const float2*)(t2 + (size_t)bh * MM * DD) + dp;
    float a0 = 0.f, a1 = 0.f;
#pragma unroll
    for (int j = qq * 32; j < qq * 32 + 32; j++) {
        float2 tv = t2b[(size_t)j * 32];
        float pj = p[j];
        a0 += pj * tv.x;
        a1 += pj * tv.y;
    }
    sc[qq * 64 + 2 * dp]     = a0;
    sc[qq * 64 + 2 * dp + 1] = a1;
    __syncthreads();
    if (t < 64) {
        float s = 0.f;
#pragma unroll
        for (int g = 0; g < 8; g++) s += sc[g * 64 + t];
        int b_ = bh >> 3, h = bh & 7;
        oh[((size_t)(b_ * NN + i)) * DIM + h * 64 + t] = f2b(s);
    }
}

// depthwise conv residual: oh += conv(v) along n per head (w is fp32)
__global__ void conv_add(const bf16* __restrict__ v, const float* __restrict__ w,
                         bf16* __restrict__ oh) {
    int idx = blockIdx.x * 256 + threadIdx.x;   // ((b*N+i)*8 + h)*64 + d
    int d = idx & 63;
    int h = (idx >> 6) & 7;
    int rest = idx >> 9;
    int i = rest & 8191;
    int b_ = rest >> 13;
    const bf16* vb = v + ((size_t)(b_ * NH + h) * NN) * DD + d;
    float acc = 0.f;
#pragma unroll
    for (int tt = 0; tt < KER; tt++) {
        int src = i + tt - 16;
        if (src >= 0 && src < NN) acc += w[h * KER + tt] * b2f(vb[(size_t)src * DD]);
    }
    oh[idx] = f2b(b2f(oh[idx]) + acc);
}

// ---------------------------------------------------------------------------

extern "C" void kernel_launch(void* const* d_in, const int* in_sizes, int n_in,
                              void* d_out, int out_size, void* d_ws, size_t ws_size,
                              hipStream_t stream) {
    const float* x    = (const float*)d_in[0];
    const float* Wqkv = (const float*)d_in[1];
    const float* Wout = (const float*)d_in[2];
    const float* bout = (const float*)d_in[3];
    const float* cw   = (const float*)d_in[4];
    float* out = (float*)d_out;

    const size_t SZ_QKV = (size_t)BB * NH * NN * DD;   // 16,777,216 elems
    const size_t SZ_L   = (size_t)BB * NH * MM * DD;   // 524,288
    const size_t SZ_M2  = (size_t)BB * NH * MM * MM;   // 2,097,152

    // --- workspace plumbing (117,440,520 B -- proven to fit) ---
    char* p = (char*)d_ws;
    bf16* q    = (bf16*)p;  p += SZ_QKV * 2;    // 32 MB
    bf16* v    = (bf16*)p;  p += SZ_QKV * 2;    // 32 MB
    float* x2   = (float*)p; p += SZ_M2 * 4;    // 8 MB each, 40 MB total
    float* z    = (float*)p; p += SZ_M2 * 4;
    float* z2   = (float*)p; p += SZ_M2 * 4;
    float* bufA = (float*)p; p += SZ_M2 * 4;
    float* bufB = (float*)p; p += SZ_M2 * 4;
    float* qL   = (float*)p; p += SZ_L * 4;     // 2 MB each
    float* kL   = (float*)p; p += SZ_L * 4;
    float* t1   = (float*)p; p += SZ_L * 4;
    float* t2   = (float*)p; p += SZ_L * 4;
    float* scal = (float*)p; p += 2 * 4;
    size_t need = (size_t)(p - (char*)d_ws);
    bf16* k  = (bf16*)d_out;   // first 32 MB of the 64 MB fp32 out buffer
    bf16* oh = (bf16*)x2;      // 32 MB over dead pinv region

    if (ws_size < need) {
        zero_out<<<out_size / 256, 256, 0, stream>>>(out);
        return;
    }

    // 1. qkv projection + head transpose + q scaling (fp32 in, bf16 out)
    gemm_qkv<<<dim3(K3 / 64, (BB * NN) / 64), 256, 0, stream>>>(x, Wqkv, q, k, v);
    // 2. landmark means
    landmark_means<<<(BB * NH * MM * DD) / 256, 256, 0, stream>>>(q, k, qL, kL);
    // 3. attn2 = softmax(qL kL^T)
    attn2_softmax<<<BB * NH * MM, 256, 0, stream>>>(qL, kL, x2);
    // 4. pinv init scalars
    init_scal<<<1, 64, 0, stream>>>(scal);
    rsum_max<<<BB * NH * MM, 256, 0, stream>>>(x2, scal);
    csum_max<<<BB * NH, 256, 0, stream>>>(x2, scal);
    z_init<<<(int)(SZ_M2 / 256), 256, 0, stream>>>(x2, scal, z);
    // 5. Newton-Schulz pinv iterations
    for (int it = 0; it < 6; it++) {
        bgemm<<<dim3(4, 4, BB * NH), 256, 0, stream>>>(x2, z, bufA, MM, MM, MM, 1.f, 0.f);     // A = x z
        eye7_sub<<<(int)(SZ_M2 / 256), 256, 0, stream>>>(bufA, bufB);                           // B1 = 7I - A
        bgemm<<<dim3(4, 4, BB * NH), 256, 0, stream>>>(bufA, bufB, z2, MM, MM, MM, -1.f, 15.f); // Y1 = 15I - A B1
        bgemm<<<dim3(4, 4, BB * NH), 256, 0, stream>>>(bufA, z2, bufB, MM, MM, MM, -1.f, 13.f); // Y2 = 13I - A Y1
        bgemm<<<dim3(4, 4, BB * NH), 256, 0, stream>>>(z, bufB, z2, MM, MM, MM, 0.25f, 0.f);    // z' = 0.25 z Y2
        float* tmp = z; z = z2; z2 = tmp;
    }
    // 6. t1 = softmax(qL k^T) @ v   (k dead after this)
    attn3v_kernel<<<BB * NH * MM, 256, 0, stream>>>(qL, k, v, t1);
    // 7. t2 = z @ t1
    bgemm<<<dim3(1, 4, BB * NH), 256, 0, stream>>>(z, t1, t2, MM, DD, MM, 1.f, 0.f);
    // 8. oh = softmax(q kL^T) @ t2
    attn1_out<<<BB * NH * NN, 256, 0, stream>>>(q, kL, t2, oh);
    // 9. oh += depthwise conv residual
    conv_add<<<(BB * NN * DIM) / 256, 256, 0, stream>>>(v, cw, oh);
    // 10. out = oh @ Wout + bout   (fully overwrites d_out; k dead)
    gemm_out<<<dim3(DIM / 64, (BB * NN) / 64), 256, 0, stream>>>(oh, Wout, bout, out);

    (void)in_sizes; (void)n_in; (void)ws_size;
}

// Round 6
// 4478.784 us; speedup vs baseline: 2.6032x; 1.5964x over previous
//
#include <hip/hip_runtime.h>
#include <hip/hip_bf16.h>
#include <math.h>

// Problem constants
#define BB 4
#define NH 8
#define NN 8192
#define DD 64
#define MM 256
#define LG 32
#define DIM 512
#define K3 1536
#define KER 33

typedef __hip_bfloat16 bf16;
typedef __attribute__((ext_vector_type(8))) short bf16x8;
typedef __attribute__((ext_vector_type(4))) float f32x4;

__device__ __forceinline__ float b2f(bf16 x) { return __bfloat162float(x); }
__device__ __forceinline__ bf16 f2b(float x) { return __float2bfloat16(x); }
__device__ __forceinline__ short f2bs(float x) { bf16 h = __float2bfloat16(x); return *reinterpret_cast<short*>(&h); }
// bf16-pair unpack from a uint32
__device__ __forceinline__ float blo(unsigned int u) { return __uint_as_float(u << 16); }
__device__ __forceinline__ float bhi(unsigned int u) { return __uint_as_float(u & 0xffff0000u); }

// diagnostic fallback: zero the output
__global__ void zero_out(float* __restrict__ o) {
    o[(size_t)blockIdx.x * 256 + threadIdx.x] = 0.f;
}

// ---------------------------------------------------------------------------
// qkv projection: X[32768,512](f32) @ W[512,1536](f32) -> q,k,v [b,h,n,d] bf16
// ---------------------------------------------------------------------------
__global__ void gemm_qkv(const float* __restrict__ X, const float* __restrict__ W,
                         bf16* __restrict__ q, bf16* __restrict__ k, bf16* __restrict__ v) {
    __shared__ float As[16][64];
    __shared__ float Bs[16][64];
    int tid = threadIdx.x;
    int rowBase = blockIdx.y * 64;
    int colBase = blockIdx.x * 64;
    int ty = tid >> 4, tx = tid & 15;
    float acc[4][4] = {};
    for (int k0 = 0; k0 < DIM; k0 += 16) {
        for (int idx = tid; idx < 64 * 16; idx += 256) {
            int r = idx >> 4, c = idx & 15;
            As[c][r] = X[(size_t)(rowBase + r) * DIM + k0 + c];
        }
        for (int idx = tid; idx < 16 * 64; idx += 256) {
            int r = idx >> 6, c = idx & 63;
            Bs[r][c] = W[(size_t)(k0 + r) * K3 + colBase + c];
        }
        __syncthreads();
#pragma unroll
        for (int kk = 0; kk < 16; kk++) {
            float a[4], b[4];
#pragma unroll
            for (int i = 0; i < 4; i++) a[i] = As[kk][ty * 4 + i];
#pragma unroll
            for (int j = 0; j < 4; j++) b[j] = Bs[kk][tx * 4 + j];
#pragma unroll
            for (int i = 0; i < 4; i++)
#pragma unroll
                for (int j = 0; j < 4; j++) acc[i][j] += a[i] * b[j];
        }
        __syncthreads();
    }
#pragma unroll
    for (int i = 0; i < 4; i++) {
        int r = rowBase + ty * 4 + i;
        int b_ = r >> 13, n_ = r & 8191;
#pragma unroll
        for (int j = 0; j < 4; j++) {
            int c = colBase + tx * 4 + j;
            int part = c / 512, rem = c & 511;
            int h = rem >> 6, d = rem & 63;
            size_t di = ((size_t)(b_ * NH + h) * NN + n_) * DD + d;
            float val = acc[i][j];
            if (part == 0) q[di] = f2b(val * 0.125f);      // scale = d^-0.5
            else if (part == 1) k[di] = f2b(val);
            else v[di] = f2b(val);
        }
    }
}

// out projection: OH[32768,512](bf16) @ Wout[512,512](f32) + bout -> out (f32)
__global__ void gemm_out(const bf16* __restrict__ A, const float* __restrict__ W,
                         const float* __restrict__ bias, float* __restrict__ C) {
    __shared__ float As[16][64];
    __shared__ float Bs[16][64];
    int tid = threadIdx.x;
    int rowBase = blockIdx.y * 64;
    int colBase = blockIdx.x * 64;
    int ty = tid >> 4, tx = tid & 15;
    float acc[4][4] = {};
    for (int k0 = 0; k0 < DIM; k0 += 16) {
        for (int idx = tid; idx < 64 * 16; idx += 256) {
            int r = idx >> 4, c = idx & 15;
            As[c][r] = b2f(A[(size_t)(rowBase + r) * DIM + k0 + c]);
        }
        for (int idx = tid; idx < 16 * 64; idx += 256) {
            int r = idx >> 6, c = idx & 63;
            Bs[r][c] = W[(size_t)(k0 + r) * DIM + colBase + c];
        }
        __syncthreads();
#pragma unroll
        for (int kk = 0; kk < 16; kk++) {
            float a[4], b[4];
#pragma unroll
            for (int i = 0; i < 4; i++) a[i] = As[kk][ty * 4 + i];
#pragma unroll
            for (int j = 0; j < 4; j++) b[j] = Bs[kk][tx * 4 + j];
#pragma unroll
            for (int i = 0; i < 4; i++)
#pragma unroll
                for (int j = 0; j < 4; j++) acc[i][j] += a[i] * b[j];
        }
        __syncthreads();
    }
#pragma unroll
    for (int i = 0; i < 4; i++) {
        int r = rowBase + ty * 4 + i;
#pragma unroll
        for (int j = 0; j < 4; j++) {
            int c = colBase + tx * 4 + j;
            C[(size_t)r * DIM + c] = acc[i][j] + bias[c];
        }
    }
}

// Batched fp32 GEMM: per batch z: C = scale*(A@B) + alpha*I.
__global__ void bgemm(const float* __restrict__ A, const float* __restrict__ B,
                      float* __restrict__ C, int Mm, int Nn, int Kk,
                      float scale, float alpha) {
    __shared__ float As[16][64];
    __shared__ float Bs[16][64];
    int bat = blockIdx.z;
    const float* Ab = A + (size_t)bat * Mm * Kk;
    const float* Bb = B + (size_t)bat * Kk * Nn;
    float* Cb = C + (size_t)bat * Mm * Nn;
    int tid = threadIdx.x;
    int rowBase = blockIdx.y * 64;
    int colBase = blockIdx.x * 64;
    int ty = tid >> 4, tx = tid & 15;
    float acc[4][4] = {};
    for (int k0 = 0; k0 < Kk; k0 += 16) {
        for (int idx = tid; idx < 64 * 16; idx += 256) {
            int r = idx >> 4, c = idx & 15;
            As[c][r] = Ab[(size_t)(rowBase + r) * Kk + k0 + c];
        }
        for (int idx = tid; idx < 16 * 64; idx += 256) {
            int r = idx >> 6, c = idx & 63;
            Bs[r][c] = Bb[(size_t)(k0 + r) * Nn + colBase + c];
        }
        __syncthreads();
#pragma unroll
        for (int kk = 0; kk < 16; kk++) {
            float a[4], b[4];
#pragma unroll
            for (int i = 0; i < 4; i++) a[i] = As[kk][ty * 4 + i];
#pragma unroll
            for (int j = 0; j < 4; j++) b[j] = Bs[kk][tx * 4 + j];
#pragma unroll
            for (int i = 0; i < 4; i++)
#pragma unroll
                for (int j = 0; j < 4; j++) acc[i][j] += a[i] * b[j];
        }
        __syncthreads();
    }
#pragma unroll
    for (int i = 0; i < 4; i++) {
        int r = rowBase + ty * 4 + i;
#pragma unroll
        for (int j = 0; j < 4; j++) {
            int c = colBase + tx * 4 + j;
            float val = scale * acc[i][j];
            if (r == c) val += alpha;
            Cb[(size_t)r * Nn + c] = val;
        }
    }
}

// t2t = (z @ t1)^T per batch, stored bf16 [bh][d=64][landmark=256]
__global__ void bgemm_t2t(const float* __restrict__ A, const float* __restrict__ B,
                          short* __restrict__ T) {
    __shared__ float As[16][64];
    __shared__ float Bs[16][64];
    int bat = blockIdx.z;
    const float* Ab = A + (size_t)bat * MM * MM;   // z [256,256]
    const float* Bb = B + (size_t)bat * MM * DD;   // t1 [256,64]
    short* Tb = T + (size_t)bat * DD * MM;
    int tid = threadIdx.x;
    int rowBase = blockIdx.y * 64;
    int ty = tid >> 4, tx = tid & 15;
    float acc[4][4] = {};
    for (int k0 = 0; k0 < MM; k0 += 16) {
        for (int idx = tid; idx < 64 * 16; idx += 256) {
            int r = idx >> 4, c = idx & 15;
            As[c][r] = Ab[(size_t)(rowBase + r) * MM + k0 + c];
        }
        for (int idx = tid; idx < 16 * 64; idx += 256) {
            int r = idx >> 6, c = idx & 63;
            Bs[r][c] = Bb[(size_t)(k0 + r) * DD + c];
        }
        __syncthreads();
#pragma unroll
        for (int kk = 0; kk < 16; kk++) {
            float a[4], b[4];
#pragma unroll
            for (int i = 0; i < 4; i++) a[i] = As[kk][ty * 4 + i];
#pragma unroll
            for (int j = 0; j < 4; j++) b[j] = Bs[kk][tx * 4 + j];
#pragma unroll
            for (int i = 0; i < 4; i++)
#pragma unroll
                for (int j = 0; j < 4; j++) acc[i][j] += a[i] * b[j];
        }
        __syncthreads();
    }
#pragma unroll
    for (int i = 0; i < 4; i++) {
        int r = rowBase + ty * 4 + i;     // landmark
#pragma unroll
        for (int j = 0; j < 4; j++) {
            int c = tx * 4 + j;           // d
            Tb[(size_t)c * MM + r] = f2bs(acc[i][j]);
        }
    }
}

// ---------------------------------------------------------------------------
// landmark means: qL/kL[bh,mi,d] = mean over 32 tokens (bf16 in, fp32 out)
__global__ void landmark_means(const bf16* __restrict__ q, const bf16* __restrict__ k,
                               float* __restrict__ qL, float* __restrict__ kL) {
    int idx = blockIdx.x * 256 + threadIdx.x;   // (bh*256 + mi)*64 + d
    int d = idx & 63;
    int mi = (idx >> 6) & 255;
    int bh = idx >> 14;
    const bf16* qp = q + ((size_t)bh * NN + mi * LG) * DD + d;
    const bf16* kp = k + ((size_t)bh * NN + mi * LG) * DD + d;
    float sq = 0.f, sk = 0.f;
#pragma unroll
    for (int j = 0; j < LG; j++) { sq += b2f(qp[(size_t)j * DD]); sk += b2f(kp[(size_t)j * DD]); }
    qL[idx] = sq * (1.f / LG);
    kL[idx] = sk * (1.f / LG);
}

// attn2 = softmax(qL @ kL^T), one block per row (all fp32)
__global__ void attn2_softmax(const float* __restrict__ qL, const float* __restrict__ kL,
                              float* __restrict__ x2) {
    __shared__ float qs[64];
    __shared__ float red[256];
    int bh = blockIdx.x >> 8, i = blockIdx.x & 255;
    int t = threadIdx.x;
    if (t < 64) qs[t] = qL[((size_t)bh * MM + i) * DD + t];
    __syncthreads();
    const float4* kp = (const float4*)(kL + ((size_t)bh * MM + t) * DD);
    float l = 0.f;
#pragma unroll
    for (int u = 0; u < 16; u++) {
        float4 kv = kp[u];
        l += qs[u*4+0]*kv.x + qs[u*4+1]*kv.y + qs[u*4+2]*kv.z + qs[u*4+3]*kv.w;
    }
    red[t] = l; __syncthreads();
    for (int s = 128; s > 0; s >>= 1) { if (t < s) red[t] = fmaxf(red[t], red[t + s]); __syncthreads(); }
    float mx = red[0]; __syncthreads();
    float e = __expf(l - mx);
    red[t] = e; __syncthreads();
    for (int s = 128; s > 0; s >>= 1) { if (t < s) red[t] += red[t + s]; __syncthreads(); }
    x2[((size_t)bh * MM + i) * MM + t] = e / red[0];
}

__global__ void init_scal(float* scal) {
    if (threadIdx.x == 0) { scal[0] = 0.f; scal[1] = 0.f; }
}

// max over (bh,i) of sum_j |x|  -> scal[0]
__global__ void rsum_max(const float* __restrict__ x2, float* scal) {
    __shared__ float red[256];
    int t = threadIdx.x;
    float v = fabsf(x2[(size_t)blockIdx.x * MM + t]);
    red[t] = v; __syncthreads();
    for (int s = 128; s > 0; s >>= 1) { if (t < s) red[t] += red[t + s]; __syncthreads(); }
    if (t == 0) atomicMax((unsigned int*)&scal[0], __float_as_uint(red[0]));
}

// max over (bh,j) of sum_i |x|  -> scal[1]
__global__ void csum_max(const float* __restrict__ x2, float* scal) {
    __shared__ float red[256];
    int t = threadIdx.x;
    const float* xp = x2 + (size_t)blockIdx.x * MM * MM;
    float s = 0.f;
    for (int i = 0; i < MM; i++) s += fabsf(xp[(size_t)i * MM + t]);
    red[t] = s; __syncthreads();
    for (int st = 128; st > 0; st >>= 1) { if (t < st) red[t] = fmaxf(red[t], red[t + st]); __syncthreads(); }
    if (t == 0) atomicMax((unsigned int*)&scal[1], __float_as_uint(red[0]));
}

// z = x^T / (scal0*scal1 + 1e-12)
__global__ void z_init(const float* __restrict__ x2, const float* __restrict__ scal,
                       float* __restrict__ z) {
    size_t idx = (size_t)blockIdx.x * 256 + threadIdx.x;
    int j = idx & 255;
    int i = (idx >> 8) & 255;
    size_t bh = idx >> 16;
    float inv = 1.0f / (scal[0] * scal[1] + 1e-12f);
    z[idx] = x2[(bh << 16) + ((size_t)j << 8) + i] * inv;
}

// Bo = 7I - A   (elementwise over batched 256x256)
__global__ void eye7_sub(const float* __restrict__ A, float* __restrict__ Bo) {
    size_t idx = (size_t)blockIdx.x * 256 + threadIdx.x;
    int j = idx & 255;
    int i = (idx >> 8) & 255;
    Bo[idx] = ((i == j) ? 7.0f : 0.0f) - A[idx];
}

// ---------------------------------------------------------------------------
// t1 = softmax(qL @ k^T, axis=n) @ v  -- one block per (bh, landmark row)
__global__ void attn3v_kernel(const float* __restrict__ qL, const bf16* __restrict__ k,
                              const bf16* __restrict__ v, float* __restrict__ t1) {
    __shared__ float p[NN];
    __shared__ float red[256];
    __shared__ float qs[64];
    int bh = blockIdx.x >> 8, i = blockIdx.x & 255;
    int t = threadIdx.x;
    if (t < 64) qs[t] = qL[((size_t)bh * MM + i) * DD + t];
    __syncthreads();
    int sub = t & 7;
    int jofs = t >> 3;
    float qr[8];
#pragma unroll
    for (int u = 0; u < 8; u++) qr[u] = qs[sub * 8 + u];
    const uint4* kb = (const uint4*)(k + (size_t)bh * NN * DD);
    float lmax = -1e30f;
#pragma unroll 4
    for (int j0 = 0; j0 < NN; j0 += 32) {
        int j = j0 + jofs;
        uint4 pk = kb[(size_t)j * 8 + sub];
        float l;
        l  = qr[0] * blo(pk.x) + qr[1] * bhi(pk.x);
        l += qr[2] * blo(pk.y) + qr[3] * bhi(pk.y);
        l += qr[4] * blo(pk.z) + qr[5] * bhi(pk.z);
        l += qr[6] * blo(pk.w) + qr[7] * bhi(pk.w);
        l += __shfl_xor(l, 1);
        l += __shfl_xor(l, 2);
        l += __shfl_xor(l, 4);
        if (sub == 0) p[j] = l;
        lmax = fmaxf(lmax, l);
    }
    red[t] = lmax; __syncthreads();
    for (int s = 128; s > 0; s >>= 1) { if (t < s) red[t] = fmaxf(red[t], red[t + s]); __syncthreads(); }
    float mx = red[0]; __syncthreads();
    float lsum = 0.f;
    for (int j = t; j < NN; j += 256) { float e = __expf(p[j] - mx); p[j] = e; lsum += e; }
    red[t] = lsum; __syncthreads();
    for (int s = 128; s > 0; s >>= 1) { if (t < s) red[t] += red[t + s]; __syncthreads(); }
    float inv = 1.0f / red[0];
    __syncthreads();
    int dp = t & 31;
    int qq = t >> 5;
    const unsigned int* vb = (const unsigned int*)(v + (size_t)bh * NN * DD) + dp;
    float a0 = 0.f, a1 = 0.f;
#pragma unroll 4
    for (int j = qq * 1024; j < qq * 1024 + 1024; j++) {
        unsigned int pv = vb[(size_t)j * 32];
        float pj = p[j];
        a0 += pj * blo(pv);
        a1 += pj * bhi(pv);
    }
    __syncthreads();
    p[qq * 64 + 2 * dp]     = a0;
    p[qq * 64 + 2 * dp + 1] = a1;
    __syncthreads();
    if (t < 64) {
        float s = 0.f;
#pragma unroll
        for (int g = 0; g < 8; g++) s += p[g * 64 + t];
        t1[((size_t)bh * MM + i) * DD + t] = s * inv;
    }
}

// ---------------------------------------------------------------------------
// MFMA fused attn1: oh[b,i,h*64+d] = softmax(q_i kL^T) @ t2
// Block: 64 tokens (4 waves x 16), one bh. kL and t2t staged in padded LDS.
#define KLS 72    // 64 + 8 pad (rows 144 B, 16B-aligned, conflict-free b128)
#define T2S 264   // 256 + 8 pad (rows 528 B)
__global__ __launch_bounds__(256, 1) void attn1_mfma(
        const bf16* __restrict__ q, const float* __restrict__ kL,
        const short* __restrict__ t2t, bf16* __restrict__ oh) {
    __shared__ short kls[MM * KLS];        // 36 KB  [landmark][d]
    __shared__ short t2s[DD * T2S];        // 33 KB  [d][landmark]
    __shared__ short ps[4][16 * T2S];      // 33 KB  per-wave P tile [token][landmark]
    int bh = blockIdx.y;
    int n0 = blockIdx.x * 64;
    int tid = threadIdx.x;
    // stage kL (fp32 -> bf16) into padded LDS
    const float* kLb = kL + (size_t)bh * MM * DD;
    for (int idx = tid; idx < MM * DD; idx += 256) {
        int l = idx >> 6, d = idx & 63;
        kls[l * KLS + d] = f2bs(kLb[idx]);
    }
    // stage t2t (bf16) into padded LDS, 2 elems per uint
    const unsigned int* t2b = (const unsigned int*)(t2t + (size_t)bh * DD * MM);
    for (int idx = tid; idx < DD * MM / 2; idx += 256) {
        int c = idx >> 7, r = (idx & 127) * 2;
        *(unsigned int*)&t2s[c * T2S + r] = t2b[idx];
    }
    __syncthreads();
    int wave = tid >> 6, lane = tid & 63;
    int ln = lane & 15, quad = lane >> 4;
    int m = n0 + wave * 16 + ln;
    // A-fragments from q (global, bf16)
    const bf16* qrow = q + ((size_t)bh * NN + m) * DD;
    bf16x8 a0 = *(const bf16x8*)(qrow + quad * 8);
    bf16x8 a1 = *(const bf16x8*)(qrow + 32 + quad * 8);
    // QK^T: 16 n-tiles of 16 landmarks
    f32x4 acc[16];
#pragma unroll
    for (int nt = 0; nt < 16; nt++) {
        const short* kp = &kls[(nt * 16 + ln) * KLS + quad * 8];
        bf16x8 b0 = *(const bf16x8*)kp;
        bf16x8 b1 = *(const bf16x8*)(kp + 32);
        f32x4 c = {0.f, 0.f, 0.f, 0.f};
        c = __builtin_amdgcn_mfma_f32_16x16x32_bf16(a0, b0, c, 0, 0, 0);
        c = __builtin_amdgcn_mfma_f32_16x16x32_bf16(a1, b1, c, 0, 0, 0);
        acc[nt] = c;
    }
    // row softmax (rows = quad*4+r), reduce over cols: in-lane then lanes ln 0..15
    float inv[4];
#pragma unroll
    for (int r = 0; r < 4; r++) {
        float v = -1e30f;
#pragma unroll
        for (int nt = 0; nt < 16; nt++) v = fmaxf(v, acc[nt][r]);
        v = fmaxf(v, __shfl_xor(v, 1));
        v = fmaxf(v, __shfl_xor(v, 2));
        v = fmaxf(v, __shfl_xor(v, 4));
        v = fmaxf(v, __shfl_xor(v, 8));
        float s = 0.f;
#pragma unroll
        for (int nt = 0; nt < 16; nt++) { float e = __expf(acc[nt][r] - v); acc[nt][r] = e; s += e; }
        s += __shfl_xor(s, 1);
        s += __shfl_xor(s, 2);
        s += __shfl_xor(s, 4);
        s += __shfl_xor(s, 8);
        inv[r] = 1.0f / s;
    }
    // P (unnormalized) -> LDS in [token][landmark] layout (A-operand staging)
    short* pw = &ps[wave][0];
#pragma unroll
    for (int nt = 0; nt < 16; nt++)
#pragma unroll
        for (int r = 0; r < 4; r++)
            pw[(quad * 4 + r) * T2S + nt * 16 + ln] = f2bs(acc[nt][r]);
    __syncthreads();
    // PV: D[16 tokens][64 d], K=256 in 8 steps
    f32x4 o[4];
#pragma unroll
    for (int nt = 0; nt < 4; nt++) o[nt] = (f32x4){0.f, 0.f, 0.f, 0.f};
#pragma unroll
    for (int ks = 0; ks < 8; ks++) {
        bf16x8 pa = *(const bf16x8*)&pw[ln * T2S + ks * 32 + quad * 8];
#pragma unroll
        for (int nt = 0; nt < 4; nt++) {
            bf16x8 pb = *(const bf16x8*)&t2s[(nt * 16 + ln) * T2S + ks * 32 + quad * 8];
            o[nt] = __builtin_amdgcn_mfma_f32_16x16x32_bf16(pa, pb, o[nt], 0, 0, 0);
        }
    }
    // store: row = quad*4+r (same lane group as inv[r]), col = nt*16+ln
    int b_ = bh >> 3, h = bh & 7;
#pragma unroll
    for (int nt = 0; nt < 4; nt++)
#pragma unroll
        for (int r = 0; r < 4; r++) {
            int row = n0 + wave * 16 + quad * 4 + r;
            int col = nt * 16 + ln;
            oh[((size_t)(b_ * NN + row)) * DIM + h * 64 + col] = f2b(o[nt][r] * inv[r]);
        }
}

// depthwise conv residual: oh += conv(v) along n per head (w is fp32)
__global__ void conv_add(const bf16* __restrict__ v, const float* __restrict__ w,
                         bf16* __restrict__ oh) {
    int idx = blockIdx.x * 256 + threadIdx.x;   // ((b*N+i)*8 + h)*64 + d
    int d = idx & 63;
    int h = (idx >> 6) & 7;
    int rest = idx >> 9;
    int i = rest & 8191;
    int b_ = rest >> 13;
    const bf16* vb = v + ((size_t)(b_ * NH + h) * NN) * DD + d;
    float acc = 0.f;
#pragma unroll
    for (int tt = 0; tt < KER; tt++) {
        int src = i + tt - 16;
        if (src >= 0 && src < NN) acc += w[h * KER + tt] * b2f(vb[(size_t)src * DD]);
    }
    oh[idx] = f2b(b2f(oh[idx]) + acc);
}

// ---------------------------------------------------------------------------

extern "C" void kernel_launch(void* const* d_in, const int* in_sizes, int n_in,
                              void* d_out, int out_size, void* d_ws, size_t ws_size,
                              hipStream_t stream) {
    const float* x    = (const float*)d_in[0];
    const float* Wqkv = (const float*)d_in[1];
    const float* Wout = (const float*)d_in[2];
    const float* bout = (const float*)d_in[3];
    const float* cw   = (const float*)d_in[4];
    float* out = (float*)d_out;

    const size_t SZ_QKV = (size_t)BB * NH * NN * DD;   // 16,777,216 elems
    const size_t SZ_L   = (size_t)BB * NH * MM * DD;   // 524,288
    const size_t SZ_M2  = (size_t)BB * NH * MM * MM;   // 2,097,152

    // --- workspace plumbing (117,440,520 B -- proven to fit) ---
    char* p = (char*)d_ws;
    bf16* q    = (bf16*)p;  p += SZ_QKV * 2;    // 32 MB
    bf16* v    = (bf16*)p;  p += SZ_QKV * 2;    // 32 MB
    float* x2   = (float*)p; p += SZ_M2 * 4;    // 8 MB each, 40 MB total
    float* z    = (float*)p; p += SZ_M2 * 4;
    float* z2   = (float*)p; p += SZ_M2 * 4;
    float* bufA = (float*)p; p += SZ_M2 * 4;
    float* bufB = (float*)p; p += SZ_M2 * 4;
    float* qL   = (float*)p; p += SZ_L * 4;     // 2 MB each
    float* kL   = (float*)p; p += SZ_L * 4;
    float* t1   = (float*)p; p += SZ_L * 4;
    short* t2t  = (short*)p; p += SZ_L * 4;     // bf16 t2^T uses half the slot
    float* scal = (float*)p; p += 2 * 4;
    size_t need = (size_t)(p - (char*)d_ws);
    bf16* k  = (bf16*)d_out;   // first 32 MB of the 64 MB fp32 out buffer
    bf16* oh = (bf16*)x2;      // 32 MB over dead pinv region

    if (ws_size < need) {
        zero_out<<<out_size / 256, 256, 0, stream>>>(out);
        return;
    }

    // 1. qkv projection + head transpose + q scaling (fp32 in, bf16 out)
    gemm_qkv<<<dim3(K3 / 64, (BB * NN) / 64), 256, 0, stream>>>(x, Wqkv, q, k, v);
    // 2. landmark means
    landmark_means<<<(BB * NH * MM * DD) / 256, 256, 0, stream>>>(q, k, qL, kL);
    // 3. attn2 = softmax(qL kL^T)
    attn2_softmax<<<BB * NH * MM, 256, 0, stream>>>(qL, kL, x2);
    // 4. pinv init scalars
    init_scal<<<1, 64, 0, stream>>>(scal);
    rsum_max<<<BB * NH * MM, 256, 0, stream>>>(x2, scal);
    csum_max<<<BB * NH, 256, 0, stream>>>(x2, scal);
    z_init<<<(int)(SZ_M2 / 256), 256, 0, stream>>>(x2, scal, z);
    // 5. Newton-Schulz pinv iterations
    for (int it = 0; it < 6; it++) {
        bgemm<<<dim3(4, 4, BB * NH), 256, 0, stream>>>(x2, z, bufA, MM, MM, MM, 1.f, 0.f);     // A = x z
        eye7_sub<<<(int)(SZ_M2 / 256), 256, 0, stream>>>(bufA, bufB);                           // B1 = 7I - A
        bgemm<<<dim3(4, 4, BB * NH), 256, 0, stream>>>(bufA, bufB, z2, MM, MM, MM, -1.f, 15.f); // Y1 = 15I - A B1
        bgemm<<<dim3(4, 4, BB * NH), 256, 0, stream>>>(bufA, z2, bufB, MM, MM, MM, -1.f, 13.f); // Y2 = 13I - A Y1
        bgemm<<<dim3(4, 4, BB * NH), 256, 0, stream>>>(z, bufB, z2, MM, MM, MM, 0.25f, 0.f);    // z' = 0.25 z Y2
        float* tmp = z; z = z2; z2 = tmp;
    }
    // 6. t1 = softmax(qL k^T) @ v   (k dead after this)
    attn3v_kernel<<<BB * NH * MM, 256, 0, stream>>>(qL, k, v, t1);
    // 7. t2t = (z @ t1)^T in bf16 [bh][64][256]
    bgemm_t2t<<<dim3(1, 4, BB * NH), 256, 0, stream>>>(z, t1, t2t);
    // 8. oh = softmax(q kL^T) @ t2   (MFMA fused, 64 tokens/block)
    attn1_mfma<<<dim3(NN / 64, BB * NH), 256, 0, stream>>>(q, kL, t2t, oh);
    // 9. oh += depthwise conv residual
    conv_add<<<(BB * NN * DIM) / 256, 256, 0, stream>>>(v, cw, oh);
    // 10. out = oh @ Wout + bout   (fully overwrites d_out; k dead)
    gemm_out<<<dim3(DIM / 64, (BB * NN) / 64), 256, 0, stream>>>(oh, Wout, bout, out);

    (void)in_sizes; (void)n_in; (void)ws_size;
}

// Round 7
// 3205.095 us; speedup vs baseline: 3.6377x; 1.3974x over previous
//
#include <hip/hip_runtime.h>
#include <hip/hip_bf16.h>
#include <math.h>

// Problem constants
#define BB 4
#define NH 8
#define NN 8192
#define DD 64
#define MM 256
#define LG 32
#define DIM 512
#define K3 1536
#define KER 33

typedef __hip_bfloat16 bf16;
typedef __attribute__((ext_vector_type(8))) short bf16x8;
typedef __attribute__((ext_vector_type(4))) float f32x4;

__device__ __forceinline__ float b2f(bf16 x) { return __bfloat162float(x); }
__device__ __forceinline__ bf16 f2b(float x) { return __float2bfloat16(x); }
__device__ __forceinline__ short f2bs(float x) { bf16 h = __float2bfloat16(x); return *reinterpret_cast<short*>(&h); }
// bf16-pair unpack from a uint32
__device__ __forceinline__ float blo(unsigned int u) { return __uint_as_float(u << 16); }
__device__ __forceinline__ float bhi(unsigned int u) { return __uint_as_float(u & 0xffff0000u); }

// diagnostic fallback: zero the output
__global__ void zero_out(float* __restrict__ o) {
    o[(size_t)blockIdx.x * 256 + threadIdx.x] = 0.f;
}

// ---------------------------------------------------------------------------
// qkv projection: X[32768,512](f32) @ W[512,1536](f32) -> q,k,v [b,h,n,d] bf16
// ---------------------------------------------------------------------------
__global__ void gemm_qkv(const float* __restrict__ X, const float* __restrict__ W,
                         bf16* __restrict__ q, bf16* __restrict__ k, bf16* __restrict__ v) {
    __shared__ float As[16][64];
    __shared__ float Bs[16][64];
    int tid = threadIdx.x;
    int rowBase = blockIdx.y * 64;
    int colBase = blockIdx.x * 64;
    int ty = tid >> 4, tx = tid & 15;
    float acc[4][4] = {};
    for (int k0 = 0; k0 < DIM; k0 += 16) {
        for (int idx = tid; idx < 64 * 16; idx += 256) {
            int r = idx >> 4, c = idx & 15;
            As[c][r] = X[(size_t)(rowBase + r) * DIM + k0 + c];
        }
        for (int idx = tid; idx < 16 * 64; idx += 256) {
            int r = idx >> 6, c = idx & 63;
            Bs[r][c] = W[(size_t)(k0 + r) * K3 + colBase + c];
        }
        __syncthreads();
#pragma unroll
        for (int kk = 0; kk < 16; kk++) {
            float a[4], b[4];
#pragma unroll
            for (int i = 0; i < 4; i++) a[i] = As[kk][ty * 4 + i];
#pragma unroll
            for (int j = 0; j < 4; j++) b[j] = Bs[kk][tx * 4 + j];
#pragma unroll
            for (int i = 0; i < 4; i++)
#pragma unroll
                for (int j = 0; j < 4; j++) acc[i][j] += a[i] * b[j];
        }
        __syncthreads();
    }
#pragma unroll
    for (int i = 0; i < 4; i++) {
        int r = rowBase + ty * 4 + i;
        int b_ = r >> 13, n_ = r & 8191;
#pragma unroll
        for (int j = 0; j < 4; j++) {
            int c = colBase + tx * 4 + j;
            int part = c / 512, rem = c & 511;
            int h = rem >> 6, d = rem & 63;
            size_t di = ((size_t)(b_ * NH + h) * NN + n_) * DD + d;
            float val = acc[i][j];
            if (part == 0) q[di] = f2b(val * 0.125f);      // scale = d^-0.5
            else if (part == 1) k[di] = f2b(val);
            else v[di] = f2b(val);
        }
    }
}

// out projection: OH[32768,512](bf16) @ Wout[512,512](f32) + bout -> out (f32)
__global__ void gemm_out(const bf16* __restrict__ A, const float* __restrict__ W,
                         const float* __restrict__ bias, float* __restrict__ C) {
    __shared__ float As[16][64];
    __shared__ float Bs[16][64];
    int tid = threadIdx.x;
    int rowBase = blockIdx.y * 64;
    int colBase = blockIdx.x * 64;
    int ty = tid >> 4, tx = tid & 15;
    float acc[4][4] = {};
    for (int k0 = 0; k0 < DIM; k0 += 16) {
        for (int idx = tid; idx < 64 * 16; idx += 256) {
            int r = idx >> 4, c = idx & 15;
            As[c][r] = b2f(A[(size_t)(rowBase + r) * DIM + k0 + c]);
        }
        for (int idx = tid; idx < 16 * 64; idx += 256) {
            int r = idx >> 6, c = idx & 63;
            Bs[r][c] = W[(size_t)(k0 + r) * DIM + colBase + c];
        }
        __syncthreads();
#pragma unroll
        for (int kk = 0; kk < 16; kk++) {
            float a[4], b[4];
#pragma unroll
            for (int i = 0; i < 4; i++) a[i] = As[kk][ty * 4 + i];
#pragma unroll
            for (int j = 0; j < 4; j++) b[j] = Bs[kk][tx * 4 + j];
#pragma unroll
            for (int i = 0; i < 4; i++)
#pragma unroll
                for (int j = 0; j < 4; j++) acc[i][j] += a[i] * b[j];
        }
        __syncthreads();
    }
#pragma unroll
    for (int i = 0; i < 4; i++) {
        int r = rowBase + ty * 4 + i;
#pragma unroll
        for (int j = 0; j < 4; j++) {
            int c = colBase + tx * 4 + j;
            C[(size_t)r * DIM + c] = acc[i][j] + bias[c];
        }
    }
}

// Batched fp32 GEMM: per batch z: C = scale*(A@B) + alpha*I.
__global__ void bgemm(const float* __restrict__ A, const float* __restrict__ B,
                      float* __restrict__ C, int Mm, int Nn, int Kk,
                      float scale, float alpha) {
    __shared__ float As[16][64];
    __shared__ float Bs[16][64];
    int bat = blockIdx.z;
    const float* Ab = A + (size_t)bat * Mm * Kk;
    const float* Bb = B + (size_t)bat * Kk * Nn;
    float* Cb = C + (size_t)bat * Mm * Nn;
    int tid = threadIdx.x;
    int rowBase = blockIdx.y * 64;
    int colBase = blockIdx.x * 64;
    int ty = tid >> 4, tx = tid & 15;
    float acc[4][4] = {};
    for (int k0 = 0; k0 < Kk; k0 += 16) {
        for (int idx = tid; idx < 64 * 16; idx += 256) {
            int r = idx >> 4, c = idx & 15;
            As[c][r] = Ab[(size_t)(rowBase + r) * Kk + k0 + c];
        }
        for (int idx = tid; idx < 16 * 64; idx += 256) {
            int r = idx >> 6, c = idx & 63;
            Bs[r][c] = Bb[(size_t)(k0 + r) * Nn + colBase + c];
        }
        __syncthreads();
#pragma unroll
        for (int kk = 0; kk < 16; kk++) {
            float a[4], b[4];
#pragma unroll
            for (int i = 0; i < 4; i++) a[i] = As[kk][ty * 4 + i];
#pragma unroll
            for (int j = 0; j < 4; j++) b[j] = Bs[kk][tx * 4 + j];
#pragma unroll
            for (int i = 0; i < 4; i++)
#pragma unroll
                for (int j = 0; j < 4; j++) acc[i][j] += a[i] * b[j];
        }
        __syncthreads();
    }
#pragma unroll
    for (int i = 0; i < 4; i++) {
        int r = rowBase + ty * 4 + i;
#pragma unroll
        for (int j = 0; j < 4; j++) {
            int c = colBase + tx * 4 + j;
            float val = scale * acc[i][j];
            if (r == c) val += alpha;
            Cb[(size_t)r * Nn + c] = val;
        }
    }
}

// t2t = (z @ t1)^T per batch, stored bf16 [bh][d=64][landmark=256]
__global__ void bgemm_t2t(const float* __restrict__ A, const float* __restrict__ B,
                          short* __restrict__ T) {
    __shared__ float As[16][64];
    __shared__ float Bs[16][64];
    int bat = blockIdx.z;
    const float* Ab = A + (size_t)bat * MM * MM;   // z [256,256]
    const float* Bb = B + (size_t)bat * MM * DD;   // t1 [256,64]
    short* Tb = T + (size_t)bat * DD * MM;
    int tid = threadIdx.x;
    int rowBase = blockIdx.y * 64;
    int ty = tid >> 4, tx = tid & 15;
    float acc[4][4] = {};
    for (int k0 = 0; k0 < MM; k0 += 16) {
        for (int idx = tid; idx < 64 * 16; idx += 256) {
            int r = idx >> 4, c = idx & 15;
            As[c][r] = Ab[(size_t)(rowBase + r) * MM + k0 + c];
        }
        for (int idx = tid; idx < 16 * 64; idx += 256) {
            int r = idx >> 6, c = idx & 63;
            Bs[r][c] = Bb[(size_t)(k0 + r) * DD + c];
        }
        __syncthreads();
#pragma unroll
        for (int kk = 0; kk < 16; kk++) {
            float a[4], b[4];
#pragma unroll
            for (int i = 0; i < 4; i++) a[i] = As[kk][ty * 4 + i];
#pragma unroll
            for (int j = 0; j < 4; j++) b[j] = Bs[kk][tx * 4 + j];
#pragma unroll
            for (int i = 0; i < 4; i++)
#pragma unroll
                for (int j = 0; j < 4; j++) acc[i][j] += a[i] * b[j];
        }
        __syncthreads();
    }
#pragma unroll
    for (int i = 0; i < 4; i++) {
        int r = rowBase + ty * 4 + i;     // landmark
#pragma unroll
        for (int j = 0; j < 4; j++) {
            int c = tx * 4 + j;           // d
            Tb[(size_t)c * MM + r] = f2bs(acc[i][j]);
        }
    }
}

// ---------------------------------------------------------------------------
// landmark means: qL/kL[bh,mi,d] = mean over 32 tokens (bf16 in, fp32 out)
__global__ void landmark_means(const bf16* __restrict__ q, const bf16* __restrict__ k,
                               float* __restrict__ qL, float* __restrict__ kL) {
    int idx = blockIdx.x * 256 + threadIdx.x;   // (bh*256 + mi)*64 + d
    int d = idx & 63;
    int mi = (idx >> 6) & 255;
    int bh = idx >> 14;
    const bf16* qp = q + ((size_t)bh * NN + mi * LG) * DD + d;
    const bf16* kp = k + ((size_t)bh * NN + mi * LG) * DD + d;
    float sq = 0.f, sk = 0.f;
#pragma unroll
    for (int j = 0; j < LG; j++) { sq += b2f(qp[(size_t)j * DD]); sk += b2f(kp[(size_t)j * DD]); }
    qL[idx] = sq * (1.f / LG);
    kL[idx] = sk * (1.f / LG);
}

// attn2 = softmax(qL @ kL^T), one block per row (all fp32)
__global__ void attn2_softmax(const float* __restrict__ qL, const float* __restrict__ kL,
                              float* __restrict__ x2) {
    __shared__ float qs[64];
    __shared__ float red[256];
    int bh = blockIdx.x >> 8, i = blockIdx.x & 255;
    int t = threadIdx.x;
    if (t < 64) qs[t] = qL[((size_t)bh * MM + i) * DD + t];
    __syncthreads();
    const float4* kp = (const float4*)(kL + ((size_t)bh * MM + t) * DD);
    float l = 0.f;
#pragma unroll
    for (int u = 0; u < 16; u++) {
        float4 kv = kp[u];
        l += qs[u*4+0]*kv.x + qs[u*4+1]*kv.y + qs[u*4+2]*kv.z + qs[u*4+3]*kv.w;
    }
    red[t] = l; __syncthreads();
    for (int s = 128; s > 0; s >>= 1) { if (t < s) red[t] = fmaxf(red[t], red[t + s]); __syncthreads(); }
    float mx = red[0]; __syncthreads();
    float e = __expf(l - mx);
    red[t] = e; __syncthreads();
    for (int s = 128; s > 0; s >>= 1) { if (t < s) red[t] += red[t + s]; __syncthreads(); }
    x2[((size_t)bh * MM + i) * MM + t] = e / red[0];
}

__global__ void init_scal(float* scal) {
    if (threadIdx.x == 0) { scal[0] = 0.f; scal[1] = 0.f; }
}

// max over (bh,i) of sum_j |x|  -> scal[0]
__global__ void rsum_max(const float* __restrict__ x2, float* scal) {
    __shared__ float red[256];
    int t = threadIdx.x;
    float v = fabsf(x2[(size_t)blockIdx.x * MM + t]);
    red[t] = v; __syncthreads();
    for (int s = 128; s > 0; s >>= 1) { if (t < s) red[t] += red[t + s]; __syncthreads(); }
    if (t == 0) atomicMax((unsigned int*)&scal[0], __float_as_uint(red[0]));
}

// max over (bh,j) of sum_i |x|  -> scal[1]
__global__ void csum_max(const float* __restrict__ x2, float* scal) {
    __shared__ float red[256];
    int t = threadIdx.x;
    const float* xp = x2 + (size_t)blockIdx.x * MM * MM;
    float s = 0.f;
    for (int i = 0; i < MM; i++) s += fabsf(xp[(size_t)i * MM + t]);
    red[t] = s; __syncthreads();
    for (int st = 128; st > 0; st >>= 1) { if (t < st) red[t] = fmaxf(red[t], red[t + st]); __syncthreads(); }
    if (t == 0) atomicMax((unsigned int*)&scal[1], __float_as_uint(red[0]));
}

// z = x^T / (scal0*scal1 + 1e-12)
__global__ void z_init(const float* __restrict__ x2, const float* __restrict__ scal,
                       float* __restrict__ z) {
    size_t idx = (size_t)blockIdx.x * 256 + threadIdx.x;
    int j = idx & 255;
    int i = (idx >> 8) & 255;
    size_t bh = idx >> 16;
    float inv = 1.0f / (scal[0] * scal[1] + 1e-12f);
    z[idx] = x2[(bh << 16) + ((size_t)j << 8) + i] * inv;
}

// Bo = 7I - A   (elementwise over batched 256x256)
__global__ void eye7_sub(const float* __restrict__ A, float* __restrict__ Bo) {
    size_t idx = (size_t)blockIdx.x * 256 + threadIdx.x;
    int j = idx & 255;
    int i = (idx >> 8) & 255;
    Bo[idx] = ((i == j) ? 7.0f : 0.0f) - A[idx];
}

// ---------------------------------------------------------------------------
// v transpose: vT[bh][d][n] <- v[bh][n][d].  One wave per 32-token chunk;
// coalesced row reads, 64 B contiguous per-lane writes (full sectors).
__global__ void transpose_v(const bf16* __restrict__ v, bf16* __restrict__ vT) {
    int gw = blockIdx.x * 4 + (threadIdx.x >> 6);   // global wave id
    int lane = threadIdx.x & 63;                     // = d
    int bh = gw >> 8;
    int c  = gw & 255;                               // n-chunk (32 tokens)
    const bf16* vb = v + ((size_t)bh * NN + c * 32) * DD + lane;
    unsigned short buf[32];
#pragma unroll
    for (int i = 0; i < 32; i++) buf[i] = *(const unsigned short*)(vb + (size_t)i * DD);
    bf16* dst = vT + ((size_t)bh * DD + lane) * NN + c * 32;
#pragma unroll
    for (int u = 0; u < 4; u++)
        *(uint4*)(dst + u * 8) = *(uint4*)&buf[u * 8];
}

// ---------------------------------------------------------------------------
// MFMA flash attn3v: t1 = softmax(qL @ k^T over n) @ v
// Block = 32 landmark rows (2 waves x 16) for one bh; j-loop chunks of 128.
#define NJ 128
#define KS2 72     // k-chunk LDS row stride (halfwords): 144 B, b128 2-way free
#define VS2 136    // vT-chunk row stride: 272 B
#define PS2 136    // P row stride
__global__ __launch_bounds__(128, 2) void attn3v_mfma(
        const float* __restrict__ qL, const bf16* __restrict__ k,
        const bf16* __restrict__ vT, float* __restrict__ t1) {
    __shared__ short ks[NJ * KS2];          // 18432 B  [j][d]
    __shared__ short vs[DD * VS2];          // 17408 B  [d][j]
    __shared__ short ps[2][16 * PS2];       //  8704 B  per-wave P [row][j]
    int bh = blockIdx.y;
    int r0 = blockIdx.x * 32;
    int tid = threadIdx.x;
    int wave = tid >> 6, lane = tid & 63;
    int ln = lane & 15, quad = lane >> 4;
    int m = r0 + wave * 16 + ln;
    // Q A-frags (fp32 qL -> bf16)
    const float* qrow = qL + ((size_t)bh * MM + m) * DD;
    bf16x8 a0, a1;
#pragma unroll
    for (int u = 0; u < 8; u++) {
        ((short*)&a0)[u] = f2bs(qrow[quad * 8 + u]);
        ((short*)&a1)[u] = f2bs(qrow[32 + quad * 8 + u]);
    }
    const uint4* kg = (const uint4*)(k + (size_t)bh * NN * DD);
    const uint4* vg = (const uint4*)(vT + (size_t)bh * DD * NN);
    float mrow[4], lrow[4];
    f32x4 o[4];
#pragma unroll
    for (int r = 0; r < 4; r++) { mrow[r] = -1e30f; lrow[r] = 0.f; }
#pragma unroll
    for (int ct = 0; ct < 4; ct++) o[ct] = (f32x4){0.f, 0.f, 0.f, 0.f};
    short* pw = &ps[wave][0];

    for (int j0 = 0; j0 < NN; j0 += NJ) {
        __syncthreads();
        // stage k chunk: 128 rows x 8 uint4
#pragma unroll
        for (int it = 0; it < 8; it++) {
            int idx = it * 128 + tid;
            int row = idx >> 3, c8 = idx & 7;
            uint4 pk = kg[(size_t)(j0 + row) * 8 + c8];
            *(uint4*)&ks[row * KS2 + c8 * 8] = pk;
        }
        // stage vT chunk: 64 rows x 16 uint4 (128 cols)
#pragma unroll
        for (int it = 0; it < 8; it++) {
            int idx = it * 128 + tid;
            int row = idx >> 4, c8 = idx & 15;
            uint4 pv = vg[(size_t)row * (NN / 8) + (j0 / 8) + c8];
            *(uint4*)&vs[row * VS2 + c8 * 8] = pv;
        }
        __syncthreads();
        // S = Q K^T : 8 col-tiles of 16 j
        f32x4 s[8];
#pragma unroll
        for (int ct = 0; ct < 8; ct++) {
            const short* kp = &ks[(ct * 16 + ln) * KS2 + quad * 8];
            bf16x8 b0 = *(const bf16x8*)kp;
            bf16x8 b1 = *(const bf16x8*)(kp + 32);
            f32x4 c = {0.f, 0.f, 0.f, 0.f};
            c = __builtin_amdgcn_mfma_f32_16x16x32_bf16(a0, b0, c, 0, 0, 0);
            c = __builtin_amdgcn_mfma_f32_16x16x32_bf16(a1, b1, c, 0, 0, 0);
            s[ct] = c;
        }
        // online softmax per row r (row = quad*4+r); reduce over ln lanes
#pragma unroll
        for (int r = 0; r < 4; r++) {
            float v = -1e30f;
#pragma unroll
            for (int ct = 0; ct < 8; ct++) v = fmaxf(v, s[ct][r]);
            v = fmaxf(v, __shfl_xor(v, 1));
            v = fmaxf(v, __shfl_xor(v, 2));
            v = fmaxf(v, __shfl_xor(v, 4));
            v = fmaxf(v, __shfl_xor(v, 8));
            float mn = fmaxf(mrow[r], v);
            float alpha = __expf(mrow[r] - mn);
            mrow[r] = mn;
            float psum = 0.f;
#pragma unroll
            for (int ct = 0; ct < 8; ct++) { float e = __expf(s[ct][r] - mn); s[ct][r] = e; psum += e; }
            lrow[r] = lrow[r] * alpha + psum;     // per-lane partial sum
#pragma unroll
            for (int c2 = 0; c2 < 4; c2++) o[c2][r] *= alpha;
        }
        // P -> per-wave LDS (A-operand layout); same-wave RAW handled by lgkmcnt
#pragma unroll
        for (int ct = 0; ct < 8; ct++)
#pragma unroll
            for (int r = 0; r < 4; r++)
                pw[(quad * 4 + r) * PS2 + ct * 16 + ln] = f2bs(s[ct][r]);
        // PV: O += P V, K=128 in 4 steps
#pragma unroll
        for (int kstep = 0; kstep < 4; kstep++) {
            bf16x8 pa = *(const bf16x8*)&pw[ln * PS2 + kstep * 32 + quad * 8];
#pragma unroll
            for (int ct = 0; ct < 4; ct++) {
                bf16x8 pb = *(const bf16x8*)&vs[(ct * 16 + ln) * VS2 + kstep * 32 + quad * 8];
                o[ct] = __builtin_amdgcn_mfma_f32_16x16x32_bf16(pa, pb, o[ct], 0, 0, 0);
            }
        }
    }
    // finalize l (reduce per-lane partials over the 16 ln lanes)
#pragma unroll
    for (int r = 0; r < 4; r++) {
        float l = lrow[r];
        l += __shfl_xor(l, 1);
        l += __shfl_xor(l, 2);
        l += __shfl_xor(l, 4);
        l += __shfl_xor(l, 8);
        lrow[r] = 1.0f / l;
    }
#pragma unroll
    for (int ct = 0; ct < 4; ct++)
#pragma unroll
        for (int r = 0; r < 4; r++) {
            int row = r0 + wave * 16 + quad * 4 + r;
            t1[((size_t)bh * MM + row) * DD + ct * 16 + ln] = o[ct][r] * lrow[r];
        }
}

// ---------------------------------------------------------------------------
// MFMA fused attn1: oh[b,i,h*64+d] = softmax(q_i kL^T) @ t2
#define KLS 72
#define T2S 264
__global__ __launch_bounds__(256, 1) void attn1_mfma(
        const bf16* __restrict__ q, const float* __restrict__ kL,
        const short* __restrict__ t2t, bf16* __restrict__ oh) {
    __shared__ short kls[MM * KLS];
    __shared__ short t2s[DD * T2S];
    __shared__ short ps1[4][16 * T2S];
    int bh = blockIdx.y;
    int n0 = blockIdx.x * 64;
    int tid = threadIdx.x;
    const float* kLb = kL + (size_t)bh * MM * DD;
    for (int idx = tid; idx < MM * DD; idx += 256) {
        int l = idx >> 6, d = idx & 63;
        kls[l * KLS + d] = f2bs(kLb[idx]);
    }
    const unsigned int* t2b = (const unsigned int*)(t2t + (size_t)bh * DD * MM);
    for (int idx = tid; idx < DD * MM / 2; idx += 256) {
        int c = idx >> 7, r = (idx & 127) * 2;
        *(unsigned int*)&t2s[c * T2S + r] = t2b[idx];
    }
    __syncthreads();
    int wave = tid >> 6, lane = tid & 63;
    int ln = lane & 15, quad = lane >> 4;
    int m = n0 + wave * 16 + ln;
    const bf16* qrow = q + ((size_t)bh * NN + m) * DD;
    bf16x8 a0 = *(const bf16x8*)(qrow + quad * 8);
    bf16x8 a1 = *(const bf16x8*)(qrow + 32 + quad * 8);
    f32x4 acc[16];
#pragma unroll
    for (int nt = 0; nt < 16; nt++) {
        const short* kp = &kls[(nt * 16 + ln) * KLS + quad * 8];
        bf16x8 b0 = *(const bf16x8*)kp;
        bf16x8 b1 = *(const bf16x8*)(kp + 32);
        f32x4 c = {0.f, 0.f, 0.f, 0.f};
        c = __builtin_amdgcn_mfma_f32_16x16x32_bf16(a0, b0, c, 0, 0, 0);
        c = __builtin_amdgcn_mfma_f32_16x16x32_bf16(a1, b1, c, 0, 0, 0);
        acc[nt] = c;
    }
    float inv[4];
#pragma unroll
    for (int r = 0; r < 4; r++) {
        float v = -1e30f;
#pragma unroll
        for (int nt = 0; nt < 16; nt++) v = fmaxf(v, acc[nt][r]);
        v = fmaxf(v, __shfl_xor(v, 1));
        v = fmaxf(v, __shfl_xor(v, 2));
        v = fmaxf(v, __shfl_xor(v, 4));
        v = fmaxf(v, __shfl_xor(v, 8));
        float s = 0.f;
#pragma unroll
        for (int nt = 0; nt < 16; nt++) { float e = __expf(acc[nt][r] - v); acc[nt][r] = e; s += e; }
        s += __shfl_xor(s, 1);
        s += __shfl_xor(s, 2);
        s += __shfl_xor(s, 4);
        s += __shfl_xor(s, 8);
        inv[r] = 1.0f / s;
    }
    short* pw = &ps1[wave][0];
#pragma unroll
    for (int nt = 0; nt < 16; nt++)
#pragma unroll
        for (int r = 0; r < 4; r++)
            pw[(quad * 4 + r) * T2S + nt * 16 + ln] = f2bs(acc[nt][r]);
    __syncthreads();
    f32x4 o[4];
#pragma unroll
    for (int nt = 0; nt < 4; nt++) o[nt] = (f32x4){0.f, 0.f, 0.f, 0.f};
#pragma unroll
    for (int ks = 0; ks < 8; ks++) {
        bf16x8 pa = *(const bf16x8*)&pw[ln * T2S + ks * 32 + quad * 8];
#pragma unroll
        for (int nt = 0; nt < 4; nt++) {
            bf16x8 pb = *(const bf16x8*)&t2s[(nt * 16 + ln) * T2S + ks * 32 + quad * 8];
            o[nt] = __builtin_amdgcn_mfma_f32_16x16x32_bf16(pa, pb, o[nt], 0, 0, 0);
        }
    }
    int b_ = bh >> 3, h = bh & 7;
#pragma unroll
    for (int nt = 0; nt < 4; nt++)
#pragma unroll
        for (int r = 0; r < 4; r++) {
            int row = n0 + wave * 16 + quad * 4 + r;
            int col = nt * 16 + ln;
            oh[((size_t)(b_ * NN + row)) * DIM + h * 64 + col] = f2b(o[nt][r] * inv[r]);
        }
}

// depthwise conv residual: oh += conv(v) along n per head (w is fp32)
__global__ void conv_add(const bf16* __restrict__ v, const float* __restrict__ w,
                         bf16* __restrict__ oh) {
    int idx = blockIdx.x * 256 + threadIdx.x;   // ((b*N+i)*8 + h)*64 + d
    int d = idx & 63;
    int h = (idx >> 6) & 7;
    int rest = idx >> 9;
    int i = rest & 8191;
    int b_ = rest >> 13;
    const bf16* vb = v + ((size_t)(b_ * NH + h) * NN) * DD + d;
    float acc = 0.f;
#pragma unroll
    for (int tt = 0; tt < KER; tt++) {
        int src = i + tt - 16;
        if (src >= 0 && src < NN) acc += w[h * KER + tt] * b2f(vb[(size_t)src * DD]);
    }
    oh[idx] = f2b(b2f(oh[idx]) + acc);
}

// ---------------------------------------------------------------------------

extern "C" void kernel_launch(void* const* d_in, const int* in_sizes, int n_in,
                              void* d_out, int out_size, void* d_ws, size_t ws_size,
                              hipStream_t stream) {
    const float* x    = (const float*)d_in[0];
    const float* Wqkv = (const float*)d_in[1];
    const float* Wout = (const float*)d_in[2];
    const float* bout = (const float*)d_in[3];
    const float* cw   = (const float*)d_in[4];
    float* out = (float*)d_out;

    const size_t SZ_QKV = (size_t)BB * NH * NN * DD;   // 16,777,216 elems
    const size_t SZ_L   = (size_t)BB * NH * MM * DD;   // 524,288
    const size_t SZ_M2  = (size_t)BB * NH * MM * MM;   // 2,097,152

    // --- workspace plumbing (117,440,520 B -- proven to fit) ---
    char* p = (char*)d_ws;
    bf16* q    = (bf16*)p;  p += SZ_QKV * 2;    // 32 MB
    bf16* v    = (bf16*)p;  p += SZ_QKV * 2;    // 32 MB
    float* x2   = (float*)p; p += SZ_M2 * 4;    // 8 MB each, 40 MB total
    float* z    = (float*)p; p += SZ_M2 * 4;
    float* z2   = (float*)p; p += SZ_M2 * 4;
    float* bufA = (float*)p; p += SZ_M2 * 4;
    float* bufB = (float*)p; p += SZ_M2 * 4;
    float* qL   = (float*)p; p += SZ_L * 4;     // 2 MB each
    float* kL   = (float*)p; p += SZ_L * 4;
    float* t1   = (float*)p; p += SZ_L * 4;
    short* t2t  = (short*)p; p += SZ_L * 4;
    float* scal = (float*)p; p += 2 * 4;
    size_t need = (size_t)(p - (char*)d_ws);
    bf16* k  = (bf16*)d_out;                     // first 32 MB of out buffer
    bf16* vT = (bf16*)d_out + SZ_QKV;            // second 32 MB of out buffer
    bf16* oh = (bf16*)x2;                        // 32 MB over dead pinv region

    if (ws_size < need) {
        zero_out<<<out_size / 256, 256, 0, stream>>>(out);
        return;
    }

    // 1. qkv projection + head transpose + q scaling (fp32 in, bf16 out)
    gemm_qkv<<<dim3(K3 / 64, (BB * NN) / 64), 256, 0, stream>>>(x, Wqkv, q, k, v);
    // 1b. vT = v^T per (bh)
    transpose_v<<<(BB * NH * MM) / 4, 256, 0, stream>>>(v, vT);
    // 2. landmark means
    landmark_means<<<(BB * NH * MM * DD) / 256, 256, 0, stream>>>(q, k, qL, kL);
    // 3. attn2 = softmax(qL kL^T)
    attn2_softmax<<<BB * NH * MM, 256, 0, stream>>>(qL, kL, x2);
    // 4. pinv init scalars
    init_scal<<<1, 64, 0, stream>>>(scal);
    rsum_max<<<BB * NH * MM, 256, 0, stream>>>(x2, scal);
    csum_max<<<BB * NH, 256, 0, stream>>>(x2, scal);
    z_init<<<(int)(SZ_M2 / 256), 256, 0, stream>>>(x2, scal, z);
    // 5. Newton-Schulz pinv iterations
    for (int it = 0; it < 6; it++) {
        bgemm<<<dim3(4, 4, BB * NH), 256, 0, stream>>>(x2, z, bufA, MM, MM, MM, 1.f, 0.f);
        eye7_sub<<<(int)(SZ_M2 / 256), 256, 0, stream>>>(bufA, bufB);
        bgemm<<<dim3(4, 4, BB * NH), 256, 0, stream>>>(bufA, bufB, z2, MM, MM, MM, -1.f, 15.f);
        bgemm<<<dim3(4, 4, BB * NH), 256, 0, stream>>>(bufA, z2, bufB, MM, MM, MM, -1.f, 13.f);
        bgemm<<<dim3(4, 4, BB * NH), 256, 0, stream>>>(z, bufB, z2, MM, MM, MM, 0.25f, 0.f);
        float* tmp = z; z = z2; z2 = tmp;
    }
    // 6. t1 = softmax(qL k^T) @ v   (MFMA flash; k, vT dead after this)
    attn3v_mfma<<<dim3(8, BB * NH), 128, 0, stream>>>(qL, k, vT, t1);
    // 7. t2t = (z @ t1)^T in bf16 [bh][64][256]
    bgemm_t2t<<<dim3(1, 4, BB * NH), 256, 0, stream>>>(z, t1, t2t);
    // 8. oh = softmax(q kL^T) @ t2   (MFMA fused)
    attn1_mfma<<<dim3(NN / 64, BB * NH), 256, 0, stream>>>(q, kL, t2t, oh);
    // 9. oh += depthwise conv residual
    conv_add<<<(BB * NN * DIM) / 256, 256, 0, stream>>>(v, cw, oh);
    // 10. out = oh @ Wout + bout   (fully overwrites d_out; k, vT dead)
    gemm_out<<<dim3(DIM / 64, (BB * NN) / 64), 256, 0, stream>>>(oh, Wout, bout, out);

    (void)in_sizes; (void)n_in; (void)ws_size;
}